// Round 1
// baseline (984.533 us; speedup 1.0000x reference)
//
#include <hip/hip_runtime.h>
#include <math.h>

#define DIM 128
#define HEADS 8
#define PLD 640   // P leading dim: slabs [h, q, k, v, xskip] * 128

// ---------------- pack Wcat (128 x 640) + Bcat(640) ----------------
__global__ void prep_weights(const float* __restrict__ gw, const float* __restrict__ wq,
                             const float* __restrict__ wk, const float* __restrict__ wv,
                             const float* __restrict__ wsk,
                             const float* __restrict__ bq, const float* __restrict__ bk,
                             const float* __restrict__ bv, const float* __restrict__ bsk,
                             float* __restrict__ Wcat, float* __restrict__ Bcat) {
  int i = blockIdx.x * 256 + threadIdx.x;
  const int WTOT = 128 * PLD;
  if (i < WTOT) {
    int k = i / PLD, jc = i - k * PLD;
    int s = jc >> 7, j = jc & 127;
    const float* w = (s == 0) ? gw : (s == 1) ? wq : (s == 2) ? wk : (s == 3) ? wv : wsk;
    Wcat[i] = w[k * 128 + j];
  } else if (i < WTOT + PLD) {
    int ib = i - WTOT;
    int s = ib >> 7, j = ib & 127;
    Bcat[ib] = (s == 0) ? 0.f : (s == 1) ? bq[j] : (s == 2) ? bk[j] : (s == 3) ? bv[j] : bsk[j];
  }
}

// ---------------- generic tiled fp32 GEMM -------------------------
// C[M x cols] = concatK(A0|A1|A2)[M x K] * B[K x cols] (+bias) (+=C)
// A slabs each have leading dim 128; B and C share leading dim ldn.
template <bool ACC, bool BIAS>
__global__ __launch_bounds__(256) void gemm_cat(
    const float* __restrict__ A0, const float* __restrict__ A1,
    const float* __restrict__ A2, const float* __restrict__ B,
    const float* __restrict__ bias, float* __restrict__ C,
    int ldn, int M, int K) {
  __shared__ float As[16][65];
  __shared__ float Bs[16][64];
  int row0 = blockIdx.x * 64;
  int col0 = blockIdx.y * 64;
  int tid = threadIdx.x;
  int tx = tid & 15, ty = tid >> 4;
  float acc[4][4] = {};
  for (int kt = 0; kt < K; kt += 16) {
#pragma unroll
    for (int i = 0; i < 4; ++i) {
      int idx = tid + i * 256;          // 0..1023 -> 64x16
      int m = idx >> 4, k = idx & 15;
      int r = row0 + m, kg = kt + k;
      int sel = kg >> 7, ko = kg & 127;
      const float* Ap = (sel == 0) ? A0 : (sel == 1) ? A1 : A2;
      As[k][m] = (r < M) ? Ap[(size_t)r * 128 + ko] : 0.f;
    }
#pragma unroll
    for (int i = 0; i < 4; ++i) {
      int idx = tid + i * 256;          // 16x64
      int k = idx >> 6, j = idx & 63;
      Bs[k][j] = B[(size_t)(kt + k) * ldn + col0 + j];
    }
    __syncthreads();
#pragma unroll
    for (int k = 0; k < 16; ++k) {
      float a[4], b[4];
#pragma unroll
      for (int ii = 0; ii < 4; ++ii) a[ii] = As[k][ty + ii * 16];
#pragma unroll
      for (int jj = 0; jj < 4; ++jj) b[jj] = Bs[k][tx + jj * 16];
#pragma unroll
      for (int ii = 0; ii < 4; ++ii)
#pragma unroll
        for (int jj = 0; jj < 4; ++jj) acc[ii][jj] += a[ii] * b[jj];
    }
    __syncthreads();
  }
#pragma unroll
  for (int ii = 0; ii < 4; ++ii) {
    int r = row0 + ty + ii * 16;
    if (r >= M) continue;
#pragma unroll
    for (int jj = 0; jj < 4; ++jj) {
      int c = col0 + tx + jj * 16;
      float v = acc[ii][jj];
      if (BIAS) v += bias[c];
      size_t off = (size_t)r * ldn + c;
      if (ACC) v += C[off];
      C[off] = v;
    }
  }
}

// ---------------- a_src / a_dst ------------------------------------
__global__ void att_ab(const float* __restrict__ P, const float* __restrict__ atts,
                       const float* __restrict__ attd, float* __restrict__ aS,
                       float* __restrict__ aD, int n) {
  int i = blockIdx.x * 256 + threadIdx.x;
  if (i >= n * HEADS) return;
  int node = i >> 3, hd = i & 7;
  const float* hrow = P + (size_t)node * PLD + hd * 16;  // slab 0 = h
  const float* s = atts + hd * 16;
  const float* d = attd + hd * 16;
  float s1 = 0.f, s2 = 0.f;
#pragma unroll
  for (int c = 0; c < 16; ++c) {
    float hv = hrow[c];
    s1 += hv * s[c];
    s2 += hv * d[c];
  }
  aS[i] = s1;
  aD[i] = s2;
}

// ---------------- CSR build ---------------------------------------
__global__ void deg_hist(const int* __restrict__ ei, int* __restrict__ deg, int E) {
  int e = blockIdx.x * 256 + threadIdx.x;
  if (e < E) atomicAdd(&deg[ei[E + e]], 1);
}

__global__ void scan_k(const int* __restrict__ deg, int* __restrict__ offs,
                       int* __restrict__ cursor, int n) {
  __shared__ int wt[4];
  __shared__ int s_carry;
  int t = threadIdx.x;
  if (t == 0) s_carry = 0;
  __syncthreads();
  for (int base = 0; base < n; base += 256) {
    int i = base + t;
    int v = (i < n) ? deg[i] : 0;
    int lane = t & 63, wid = t >> 6;
    int x = v;
#pragma unroll
    for (int d = 1; d < 64; d <<= 1) {
      int y = __shfl_up(x, d);
      if (lane >= d) x += y;
    }
    if (lane == 63) wt[wid] = x;
    __syncthreads();
    int woff = 0;
    for (int w = 0; w < wid; ++w) woff += wt[w];
    int incl = x + woff + s_carry;
    int excl = incl - v;
    if (i < n) { offs[i] = excl; cursor[i] = excl; }
    __syncthreads();
    if (t == 255) s_carry = incl;
    __syncthreads();
  }
  if (t == 0) offs[n] = s_carry;
}

__global__ void scatter_k(const int* __restrict__ ei, int* __restrict__ cursor,
                          int* __restrict__ csrc, int E) {
  int e = blockIdx.x * 256 + threadIdx.x;
  if (e >= E) return;
  int src = ei[e], dst = ei[E + e];
  int pos = atomicAdd(&cursor[dst], 1);
  csrc[pos] = src;
}

// ---------------- per-node aggregation ----------------------------
// one wave per node; lane owns channels (2*lane, 2*lane+1); head = lane>>3
__global__ __launch_bounds__(256) void aggregate(
    const float* __restrict__ P, const float* __restrict__ x,
    const float* __restrict__ aS, const float* __restrict__ aD,
    const int* __restrict__ offs, const int* __restrict__ csrc,
    const float* __restrict__ gat_b, float* __restrict__ gat_o,
    float* __restrict__ tr_o, float* __restrict__ nbr, int n) {
  int node = blockIdx.x * 4 + (threadIdx.x >> 6);
  if (node >= n) return;
  int lane = threadIdx.x & 63;
  int head = lane >> 3;
  const float* Pn = P + (size_t)node * PLD;
  float2 qv = *(const float2*)(Pn + 128 + 2 * lane);
  float adst = aD[node * HEADS + head];

  // GAT online softmax, initialized with the self-loop term
  float lg0 = aS[node * HEADS + head] + adst;
  lg0 = (lg0 > 0.f) ? lg0 : 0.2f * lg0;
  float m_g = lg0, l_g = 1.f;
  float2 hn = *(const float2*)(Pn + 2 * lane);
  float2 acc_g = hn;

  float m_t = -1e30f, l_t = 0.f;
  float2 acc_t = {0.f, 0.f};
  float2 acc_s = {0.f, 0.f};

  int e0 = offs[node], e1 = offs[node + 1];
  for (int e = e0; e < e1; ++e) {
    int src = csrc[e];
    const float* Ps = P + (size_t)src * PLD;
    // --- GAT ---
    float lg = aS[src * HEADS + head] + adst;
    lg = (lg > 0.f) ? lg : 0.2f * lg;
    float2 hs = *(const float2*)(Ps + 2 * lane);
    if (lg > m_g) {
      float sc = __expf(m_g - lg);
      acc_g.x = acc_g.x * sc + hs.x;
      acc_g.y = acc_g.y * sc + hs.y;
      l_g = l_g * sc + 1.f;
      m_g = lg;
    } else {
      float w = __expf(lg - m_g);
      acc_g.x += w * hs.x;
      acc_g.y += w * hs.y;
      l_g += w;
    }
    // --- TransformerConv ---
    float2 ks = *(const float2*)(Ps + 256 + 2 * lane);
    float part = qv.x * ks.x + qv.y * ks.y;
    part += __shfl_xor(part, 1);
    part += __shfl_xor(part, 2);
    part += __shfl_xor(part, 4);
    float tl = part * 0.25f;  // 1/sqrt(16)
    float2 vs = *(const float2*)(Ps + 384 + 2 * lane);
    if (tl > m_t) {
      float sc = __expf(m_t - tl);
      acc_t.x = acc_t.x * sc + vs.x;
      acc_t.y = acc_t.y * sc + vs.y;
      l_t = l_t * sc + 1.f;
      m_t = tl;
    } else {
      float w = __expf(tl - m_t);
      acc_t.x += w * vs.x;
      acc_t.y += w * vs.y;
      l_t += w;
    }
    // --- SAGE sum ---
    float2 xs = *(const float2*)(x + (size_t)src * DIM + 2 * lane);
    acc_s.x += xs.x;
    acc_s.y += xs.y;
  }

  // finalize
  float2 go;
  go.x = acc_g.x / l_g + gat_b[2 * lane];
  go.y = acc_g.y / l_g + gat_b[2 * lane + 1];
  *(float2*)(gat_o + (size_t)node * DIM + 2 * lane) = go;

  float2 skip = *(const float2*)(Pn + 512 + 2 * lane);
  float2 to;
  if (l_t > 0.f) {
    to.x = acc_t.x / l_t + skip.x;
    to.y = acc_t.y / l_t + skip.y;
  } else {
    to.x = skip.x;
    to.y = skip.y;
  }
  *(float2*)(tr_o + (size_t)node * DIM + 2 * lane) = to;

  float dg = fmaxf((float)(e1 - e0), 1.f);
  float inv = 1.f / dg;
  float2 nb;
  nb.x = acc_s.x * inv;
  nb.y = acc_s.y * inv;
  *(float2*)(nbr + (size_t)node * DIM + 2 * lane) = nb;
}

// ---------------- row L2 normalize (sage) -------------------------
__global__ void l2norm_rows(float* __restrict__ sraw, int n) {
  int node = blockIdx.x * 4 + (threadIdx.x >> 6);
  if (node >= n) return;
  int lane = threadIdx.x & 63;
  float2* row = (float2*)(sraw + (size_t)node * DIM);
  float2 v = row[lane];
  float ss = v.x * v.x + v.y * v.y;
#pragma unroll
  for (int d = 1; d < 64; d <<= 1) ss += __shfl_xor(ss, d);
  float nrm = fmaxf(sqrtf(ss), 1e-12f);
  float inv = 1.f / nrm;
  v.x *= inv;
  v.y *= inv;
  row[lane] = v;
}

// ---------------- in-place LayerNorm on d_out ---------------------
__global__ void ln_k(float* __restrict__ y, const float* __restrict__ g,
                     const float* __restrict__ b, int n) {
  int node = blockIdx.x * 4 + (threadIdx.x >> 6);
  if (node >= n) return;
  int lane = threadIdx.x & 63;
  float2* row = (float2*)(y + (size_t)node * DIM);
  float2 v = row[lane];
  float s = v.x + v.y;
#pragma unroll
  for (int d = 1; d < 64; d <<= 1) s += __shfl_xor(s, d);
  float mu = s * (1.f / 128.f);
  float dx = v.x - mu, dy = v.y - mu;
  float ss = dx * dx + dy * dy;
#pragma unroll
  for (int d = 1; d < 64; d <<= 1) ss += __shfl_xor(ss, d);
  float rstd = 1.f / sqrtf(ss * (1.f / 128.f) + 1e-5f);
  float2 gg = ((const float2*)g)[lane];
  float2 bb = ((const float2*)b)[lane];
  float2 o;
  o.x = dx * rstd * gg.x + bb.x;
  o.y = dy * rstd * gg.y + bb.y;
  row[lane] = o;
}

extern "C" void kernel_launch(void* const* d_in, const int* in_sizes, int n_in,
                              void* d_out, int out_size, void* d_ws, size_t ws_size,
                              hipStream_t stream) {
  const float* x      = (const float*)d_in[0];
  const int*   ei     = (const int*)d_in[1];
  const float* gat_w  = (const float*)d_in[2];
  const float* att_s  = (const float*)d_in[3];
  const float* att_d  = (const float*)d_in[4];
  const float* gat_b  = (const float*)d_in[5];
  const float* swl    = (const float*)d_in[6];
  const float* sbl    = (const float*)d_in[7];
  const float* swr    = (const float*)d_in[8];
  const float* wq     = (const float*)d_in[9];
  const float* bq     = (const float*)d_in[10];
  const float* wk     = (const float*)d_in[11];
  const float* bk     = (const float*)d_in[12];
  const float* wv     = (const float*)d_in[13];
  const float* bv     = (const float*)d_in[14];
  const float* wsk    = (const float*)d_in[15];
  const float* bsk    = (const float*)d_in[16];
  const float* fus_w  = (const float*)d_in[17];
  const float* fus_b  = (const float*)d_in[18];
  const float* ln_g   = (const float*)d_in[19];
  const float* ln_b   = (const float*)d_in[20];
  float* out = (float*)d_out;

  const int n = in_sizes[0] / DIM;  // 50000
  const int E = in_sizes[1] / 2;    // 800000

  // workspace layout (fp32 units) — ~237 MB total
  float* ws = (float*)d_ws;
  size_t o = 0;
  float* Wcat  = ws + o; o += 128 * PLD;
  float* Bcat  = ws + o; o += PLD;
  float* aS    = ws + o; o += (size_t)n * HEADS;
  float* aD    = ws + o; o += (size_t)n * HEADS;
  float* P     = ws + o; o += (size_t)n * PLD;
  float* gat_o = ws + o; o += (size_t)n * DIM;
  float* tr_o  = ws + o; o += (size_t)n * DIM;
  float* nbr   = ws + o; o += (size_t)n * DIM;
  float* sraw  = ws + o; o += (size_t)n * DIM;
  int* ideg   = (int*)(ws + o); o += n;
  int* offs   = (int*)(ws + o); o += n + 1;
  int* cursor = (int*)(ws + o); o += n;
  int* csrc   = (int*)(ws + o); o += E;

  hipMemsetAsync(ideg, 0, n * sizeof(int), stream);

  prep_weights<<<(128 * PLD + PLD + 255) / 256, 256, 0, stream>>>(
      gat_w, wq, wk, wv, wsk, bq, bk, bv, bsk, Wcat, Bcat);

  // P = x @ Wcat + Bcat   (N x 640)
  gemm_cat<false, true><<<dim3((n + 63) / 64, PLD / 64), 256, 0, stream>>>(
      x, nullptr, nullptr, Wcat, Bcat, P, PLD, n, 128);

  att_ab<<<(n * HEADS + 255) / 256, 256, 0, stream>>>(P, att_s, att_d, aS, aD, n);

  deg_hist<<<(E + 255) / 256, 256, 0, stream>>>(ei, ideg, E);
  scan_k<<<1, 256, 0, stream>>>(ideg, offs, cursor, n);
  scatter_k<<<(E + 255) / 256, 256, 0, stream>>>(ei, cursor, csrc, E);

  aggregate<<<(n + 3) / 4, 256, 0, stream>>>(P, x, aS, aD, offs, csrc, gat_b,
                                             gat_o, tr_o, nbr, n);

  // sage_raw = nbr @ wl + bl ; += x @ wr
  gemm_cat<false, true><<<dim3((n + 63) / 64, 2), 256, 0, stream>>>(
      nbr, nullptr, nullptr, swl, sbl, sraw, DIM, n, 128);
  gemm_cat<true, false><<<dim3((n + 63) / 64, 2), 256, 0, stream>>>(
      x, nullptr, nullptr, swr, nullptr, sraw, DIM, n, 128);
  l2norm_rows<<<(n + 3) / 4, 256, 0, stream>>>(sraw, n);

  // out = [gat | sage | tr] @ fus_w + fus_b ; then in-place LayerNorm
  gemm_cat<false, true><<<dim3((n + 63) / 64, 2), 256, 0, stream>>>(
      gat_o, sraw, tr_o, fus_w, fus_b, out, DIM, n, 384);
  ln_k<<<(n + 3) / 4, 256, 0, stream>>>(out, ln_g, ln_b, n);
}

// Round 2
// 659.982 us; speedup vs baseline: 1.4918x; 1.4918x over previous
//
#include <hip/hip_runtime.h>
#include <hip/hip_bf16.h>
#include <math.h>

#define DIM 128
#define HEADS 8

typedef short short8 __attribute__((ext_vector_type(8)));
typedef float f32x4 __attribute__((ext_vector_type(4)));

#define GLD_LDS16(g, l) \
  __builtin_amdgcn_global_load_lds((const __attribute__((address_space(1))) void*)(g), \
                                   (__attribute__((address_space(3))) void*)(l), 16, 0, 0)

__device__ __forceinline__ float bf2f(unsigned short u) {
  union { unsigned int i; float f; } c; c.i = ((unsigned int)u) << 16; return c.f;
}
__device__ __forceinline__ unsigned short f2bf(float f) {
  __hip_bfloat16 h = __float2bfloat16(f);
  union { __hip_bfloat16 h; unsigned short u; } c; c.h = h; return c.u;
}

// ---------------- prep: transposed bf16 weights + Bcat --------------
// Wcat_t[640][128] (bf16), sage_t[128][256], fus_t[128][384], Bcat[640] f32
__global__ void prep_w(const float* __restrict__ gw, const float* __restrict__ wq,
                       const float* __restrict__ wk, const float* __restrict__ wv,
                       const float* __restrict__ wsk,
                       const float* __restrict__ bq, const float* __restrict__ bk,
                       const float* __restrict__ bv, const float* __restrict__ bsk,
                       const float* __restrict__ swl, const float* __restrict__ swr,
                       const float* __restrict__ fw,
                       unsigned short* __restrict__ Wcat_t, float* __restrict__ Bcat,
                       unsigned short* __restrict__ sage_t, unsigned short* __restrict__ fus_t) {
  int i = blockIdx.x * 256 + threadIdx.x;
  if (i < 81920) {                      // Wcat_t: row c=i/128 (0..639), k=i%128
    int c = i >> 7, k = i & 127;
    int s = c >> 7, j = c & 127;
    const float* w = (s == 0) ? gw : (s == 1) ? wq : (s == 2) ? wk : (s == 3) ? wv : wsk;
    Wcat_t[i] = f2bf(w[k * 128 + j]);
  } else if (i < 114688) {              // sage_t: j=t/256, k=t%256
    int t = i - 81920;
    int j = t >> 8, k = t & 255;
    float v = (k < 128) ? swl[k * 128 + j] : swr[(k - 128) * 128 + j];
    sage_t[t] = f2bf(v);
  } else if (i < 163840) {              // fus_t: j=t/384, k=t%384
    int t = i - 114688;
    int j = t / 384, k = t - j * 384;
    fus_t[t] = f2bf(fw[k * 128 + j]);
  } else if (i < 164480) {              // Bcat
    int c = i - 163840;
    int s = c >> 7, j = c & 127;
    Bcat[c] = (s == 0) ? 0.f : (s == 1) ? bq[j] : (s == 2) ? bk[j] : (s == 3) ? bv[j] : bsk[j];
  }
}

// ---------------- x -> AG x-slab (bf16) -----------------------------
__global__ void convert_x(const float* __restrict__ x, unsigned short* __restrict__ AG, int n) {
  int i = blockIdx.x * 256 + threadIdx.x;         // one float4
  if (i >= n * 32) return;
  int idx = i * 4;
  float4 v = *(const float4*)(x + idx);
  ushort4 u;
  u.x = f2bf(v.x); u.y = f2bf(v.y); u.z = f2bf(v.z); u.w = f2bf(v.w);
  *(ushort4*)(AG + (size_t)(idx >> 7) * 512 + 384 + (idx & 127)) = u;
}

// ---------------- bf16 MFMA GEMM ------------------------------------
// C[M x N] = A[M x K] * Bt[N x K]^T + bias. A is bf16 (two K-slabs, boundary
// at k=128), Bt row-major [N][K] bf16. Tile 128x64, BK=32, 4 waves.
// EPI 0: proj routing (h/k/v -> AG bf16, q -> Pq f32, skip -> Pskip f32)
// EPI 1: plain f32 out.
template <int EPI>
__global__ __launch_bounds__(256) void gemm_mfma(
    const __hip_bfloat16* __restrict__ A0, int lda0,
    const __hip_bfloat16* __restrict__ A1, int lda1,
    const __hip_bfloat16* __restrict__ Bt, int K,
    const float* __restrict__ bias,
    float* __restrict__ outF, int ldo,
    unsigned short* __restrict__ AGo, float* __restrict__ Pq, float* __restrict__ Psk,
    int M, int N) {
  __shared__ char Asb[128 * 64];   // 128 rows x 32 bf16
  __shared__ char Bsb[64 * 64];    // 64 cols x 32 bf16
  int tid = threadIdx.x;
  int l = tid & 63, w = tid >> 6;
  int row0 = blockIdx.x * 128, col0 = blockIdx.y * 64;
  f32x4 acc[2][4] = {};

  for (int kt = 0; kt < K; kt += 32) {
    const __hip_bfloat16* Ap;
    int lda, kof;
    if (A1 != nullptr && kt >= 128) { Ap = A1; lda = lda1; kof = kt - 128; }
    else { Ap = A0; lda = lda0; kof = kt; }
#pragma unroll
    for (int it = 0; it < 2; ++it) {   // A: 512 16B chunks
      int c = it * 256 + tid;
      int r = c >> 2, cp = c & 3;
      int gp = cp ^ (r & 3);
      int gr = row0 + r; if (gr >= M) gr = M - 1;
      GLD_LDS16((const char*)(Ap + (size_t)gr * lda + kof) + gp * 16, Asb + c * 16);
    }
    {                                  // B: 256 16B chunks
      int c = tid;
      int r = c >> 2, cp = c & 3;
      int gp = cp ^ (r & 3);
      GLD_LDS16((const char*)(Bt + (size_t)(col0 + r) * K + kt) + gp * 16, Bsb + c * 16);
    }
    __syncthreads();
    int g = l >> 4, ri = l & 15;
    short8 af[2], bfr[4];
#pragma unroll
    for (int m = 0; m < 2; ++m) {
      int r = w * 32 + m * 16 + ri;
      af[m] = *(const short8*)(Asb + r * 64 + ((g ^ (r & 3)) * 16));
    }
#pragma unroll
    for (int c4 = 0; c4 < 4; ++c4) {
      int r = c4 * 16 + ri;
      bfr[c4] = *(const short8*)(Bsb + r * 64 + ((g ^ (r & 3)) * 16));
    }
#pragma unroll
    for (int m = 0; m < 2; ++m)
#pragma unroll
      for (int c4 = 0; c4 < 4; ++c4)
        acc[m][c4] = __builtin_amdgcn_mfma_f32_16x16x32_bf16(af[m], bfr[c4], acc[m][c4], 0, 0, 0);
    __syncthreads();
  }

  int g = l >> 4, ri = l & 15;
#pragma unroll
  for (int m = 0; m < 2; ++m) {
#pragma unroll
    for (int c4 = 0; c4 < 4; ++c4) {
#pragma unroll
      for (int j = 0; j < 4; ++j) {
        int row = row0 + w * 32 + m * 16 + g * 4 + j;
        if (row >= M) continue;
        int col = col0 + c4 * 16 + ri;
        float v = acc[m][c4][j] + bias[col];
        if (EPI == 0) {
          if (col < 128)       AGo[(size_t)row * 512 + col] = f2bf(v);
          else if (col < 256)  Pq[(size_t)row * 128 + (col - 128)] = v;
          else if (col < 512)  AGo[(size_t)row * 512 + (col - 128)] = f2bf(v);
          else                 Psk[(size_t)row * 128 + (col - 512)] = v;
        } else {
          outF[(size_t)row * ldo + col] = v;
        }
      }
    }
  }
}

// ---------------- a_src / a_dst (from bf16 h slab) ------------------
__global__ void att_ab(const unsigned short* __restrict__ AG, const float* __restrict__ atts,
                       const float* __restrict__ attd, float* __restrict__ aS,
                       float* __restrict__ aD, int n) {
  int i = blockIdx.x * 256 + threadIdx.x;
  if (i >= n * HEADS) return;
  int node = i >> 3, hd = i & 7;
  const unsigned short* hrow = AG + (size_t)node * 512 + hd * 16;
  const float* s = atts + hd * 16;
  const float* d = attd + hd * 16;
  float s1 = 0.f, s2 = 0.f;
#pragma unroll
  for (int c = 0; c < 16; ++c) {
    float hv = bf2f(hrow[c]);
    s1 += hv * s[c];
    s2 += hv * d[c];
  }
  aS[i] = s1;
  aD[i] = s2;
}

// ---------------- CSR build ----------------------------------------
__global__ void deg_hist(const int* __restrict__ ei, int* __restrict__ deg, int E) {
  int e = blockIdx.x * 256 + threadIdx.x;
  if (e < E) atomicAdd(&deg[ei[E + e]], 1);
}

__global__ void scan_k(const int* __restrict__ deg, int* __restrict__ offs,
                       int* __restrict__ cursor, int n) {
  __shared__ int wt[4];
  __shared__ int s_carry;
  int t = threadIdx.x;
  if (t == 0) s_carry = 0;
  __syncthreads();
  for (int base = 0; base < n; base += 256) {
    int i = base + t;
    int v = (i < n) ? deg[i] : 0;
    int lane = t & 63, wid = t >> 6;
    int x = v;
#pragma unroll
    for (int d = 1; d < 64; d <<= 1) {
      int y = __shfl_up(x, d);
      if (lane >= d) x += y;
    }
    if (lane == 63) wt[wid] = x;
    __syncthreads();
    int woff = 0;
    for (int wv = 0; wv < wid; ++wv) woff += wt[wv];
    int incl = x + woff + s_carry;
    int excl = incl - v;
    if (i < n) { offs[i] = excl; cursor[i] = excl; }
    __syncthreads();
    if (t == 255) s_carry = incl;
    __syncthreads();
  }
  if (t == 0) offs[n] = s_carry;
}

__global__ void scatter_k(const int* __restrict__ ei, int* __restrict__ cursor,
                          int* __restrict__ csrc, int E) {
  int e = blockIdx.x * 256 + threadIdx.x;
  if (e >= E) return;
  int src = ei[e], dst = ei[E + e];
  int pos = atomicAdd(&cursor[dst], 1);
  csrc[pos] = src;
}

// ---------------- per-node aggregation (bf16 gathers) ----------------
// AG row: [h(0:128) k(128:256) v(256:384) x(384:512)] bf16; wave per node.
__global__ __launch_bounds__(256) void aggregate(
    const unsigned short* __restrict__ AG, const float* __restrict__ Pq,
    const float* __restrict__ Psk,
    const float* __restrict__ aS, const float* __restrict__ aD,
    const int* __restrict__ offs, const int* __restrict__ csrc,
    const float* __restrict__ gat_b,
    unsigned short* __restrict__ FUS, unsigned short* __restrict__ nbrb, int n) {
  int node = blockIdx.x * 4 + (threadIdx.x >> 6);
  if (node >= n) return;
  int lane = threadIdx.x & 63;
  int head = lane >> 3;
  const unsigned short* An = AG + (size_t)node * 512;
  float2 qv;
  { float2 q = *(const float2*)(Pq + (size_t)node * 128 + 2 * lane); qv = q; }
  float adst = aD[node * HEADS + head];

  // GAT online softmax, self-loop init
  float lg0 = aS[node * HEADS + head] + adst;
  lg0 = (lg0 > 0.f) ? lg0 : 0.2f * lg0;
  float m_g = lg0, l_g = 1.f;
  ushort2 hu = *(const ushort2*)(An + 2 * lane);
  float2 acc_g = { bf2f(hu.x), bf2f(hu.y) };

  float m_t = -1e30f, l_t = 0.f;
  float2 acc_t = {0.f, 0.f};
  float2 acc_s = {0.f, 0.f};

  int e0 = offs[node], e1 = offs[node + 1];
  for (int e = e0; e < e1; ++e) {
    int src = csrc[e];
    const unsigned short* As = AG + (size_t)src * 512;
    // --- GAT ---
    float lg = aS[src * HEADS + head] + adst;
    lg = (lg > 0.f) ? lg : 0.2f * lg;
    ushort2 hs = *(const ushort2*)(As + 2 * lane);
    float hx = bf2f(hs.x), hy = bf2f(hs.y);
    if (lg > m_g) {
      float sc = __expf(m_g - lg);
      acc_g.x = acc_g.x * sc + hx;
      acc_g.y = acc_g.y * sc + hy;
      l_g = l_g * sc + 1.f;
      m_g = lg;
    } else {
      float wv = __expf(lg - m_g);
      acc_g.x += wv * hx;
      acc_g.y += wv * hy;
      l_g += wv;
    }
    // --- TransformerConv ---
    ushort2 ku = *(const ushort2*)(As + 128 + 2 * lane);
    float part = qv.x * bf2f(ku.x) + qv.y * bf2f(ku.y);
    part += __shfl_xor(part, 1);
    part += __shfl_xor(part, 2);
    part += __shfl_xor(part, 4);
    float tl = part * 0.25f;  // 1/sqrt(16)
    ushort2 vu = *(const ushort2*)(As + 256 + 2 * lane);
    float vx = bf2f(vu.x), vy = bf2f(vu.y);
    if (tl > m_t) {
      float sc = __expf(m_t - tl);
      acc_t.x = acc_t.x * sc + vx;
      acc_t.y = acc_t.y * sc + vy;
      l_t = l_t * sc + 1.f;
      m_t = tl;
    } else {
      float wv = __expf(tl - m_t);
      acc_t.x += wv * vx;
      acc_t.y += wv * vy;
      l_t += wv;
    }
    // --- SAGE sum ---
    ushort2 xu = *(const ushort2*)(As + 384 + 2 * lane);
    acc_s.x += bf2f(xu.x);
    acc_s.y += bf2f(xu.y);
  }

  // finalize: gat -> FUS[:,0:128], tr -> FUS[:,256:384], nbr -> nbrb
  float gx = acc_g.x / l_g + gat_b[2 * lane];
  float gy = acc_g.y / l_g + gat_b[2 * lane + 1];
  ushort2 go = { f2bf(gx), f2bf(gy) };
  *(ushort2*)(FUS + (size_t)node * 384 + 2 * lane) = go;

  float2 skip = *(const float2*)(Psk + (size_t)node * 128 + 2 * lane);
  float tx, ty;
  if (l_t > 0.f) {
    tx = acc_t.x / l_t + skip.x;
    ty = acc_t.y / l_t + skip.y;
  } else { tx = skip.x; ty = skip.y; }
  ushort2 to = { f2bf(tx), f2bf(ty) };
  *(ushort2*)(FUS + (size_t)node * 384 + 256 + 2 * lane) = to;

  float dg = fmaxf((float)(e1 - e0), 1.f);
  float inv = 1.f / dg;
  ushort2 nb = { f2bf(acc_s.x * inv), f2bf(acc_s.y * inv) };
  *(ushort2*)(nbrb + (size_t)node * 128 + 2 * lane) = nb;
}

// ---------------- row L2 normalize (sage) -> FUS mid slab -----------
__global__ void l2norm_rows(const float* __restrict__ sraw, unsigned short* __restrict__ FUS, int n) {
  int node = blockIdx.x * 4 + (threadIdx.x >> 6);
  if (node >= n) return;
  int lane = threadIdx.x & 63;
  float2 v = *(const float2*)(sraw + (size_t)node * 128 + 2 * lane);
  float ss = v.x * v.x + v.y * v.y;
#pragma unroll
  for (int d = 1; d < 64; d <<= 1) ss += __shfl_xor(ss, d);
  float nrm = fmaxf(sqrtf(ss), 1e-12f);
  float inv = 1.f / nrm;
  ushort2 o = { f2bf(v.x * inv), f2bf(v.y * inv) };
  *(ushort2*)(FUS + (size_t)node * 384 + 128 + 2 * lane) = o;
}

// ---------------- in-place LayerNorm on d_out -----------------------
__global__ void ln_k(float* __restrict__ y, const float* __restrict__ g,
                     const float* __restrict__ b, int n) {
  int node = blockIdx.x * 4 + (threadIdx.x >> 6);
  if (node >= n) return;
  int lane = threadIdx.x & 63;
  float2* row = (float2*)(y + (size_t)node * DIM);
  float2 v = row[lane];
  float s = v.x + v.y;
#pragma unroll
  for (int d = 1; d < 64; d <<= 1) s += __shfl_xor(s, d);
  float mu = s * (1.f / 128.f);
  float dx = v.x - mu, dy = v.y - mu;
  float ss = dx * dx + dy * dy;
#pragma unroll
  for (int d = 1; d < 64; d <<= 1) ss += __shfl_xor(ss, d);
  float rstd = 1.f / sqrtf(ss * (1.f / 128.f) + 1e-5f);
  float2 gg = ((const float2*)g)[lane];
  float2 bb = ((const float2*)b)[lane];
  float2 o;
  o.x = dx * rstd * gg.x + bb.x;
  o.y = dy * rstd * gg.y + bb.y;
  row[lane] = o;
}

extern "C" void kernel_launch(void* const* d_in, const int* in_sizes, int n_in,
                              void* d_out, int out_size, void* d_ws, size_t ws_size,
                              hipStream_t stream) {
  const float* x      = (const float*)d_in[0];
  const int*   ei     = (const int*)d_in[1];
  const float* gat_w  = (const float*)d_in[2];
  const float* att_s  = (const float*)d_in[3];
  const float* att_d  = (const float*)d_in[4];
  const float* gat_b  = (const float*)d_in[5];
  const float* swl    = (const float*)d_in[6];
  const float* sbl    = (const float*)d_in[7];
  const float* swr    = (const float*)d_in[8];
  const float* wq     = (const float*)d_in[9];
  const float* bq     = (const float*)d_in[10];
  const float* wk     = (const float*)d_in[11];
  const float* bk     = (const float*)d_in[12];
  const float* wv     = (const float*)d_in[13];
  const float* bv     = (const float*)d_in[14];
  const float* wsk    = (const float*)d_in[15];
  const float* bsk    = (const float*)d_in[16];
  const float* fus_w  = (const float*)d_in[17];
  const float* fus_b  = (const float*)d_in[18];
  const float* ln_g   = (const float*)d_in[19];
  const float* ln_b   = (const float*)d_in[20];
  float* out = (float*)d_out;

  const int n = in_sizes[0] / DIM;  // 50000
  const int E = in_sizes[1] / 2;    // 800000

  // ---- workspace carve (bytes, 256B aligned chunks) ----
  char* wsb = (char*)d_ws;
  size_t o = 0;
  auto carve = [&](size_t bytes) { char* p = wsb + o; o += (bytes + 255) & ~(size_t)255; return p; };
  unsigned short* Wcat_t = (unsigned short*)carve(640 * 128 * 2);
  float*          Bcat   = (float*)carve(640 * 4);
  unsigned short* sage_t = (unsigned short*)carve(128 * 256 * 2);
  unsigned short* fus_t  = (unsigned short*)carve(128 * 384 * 2);
  unsigned short* AG     = (unsigned short*)carve((size_t)n * 512 * 2);
  float*          Pqs    = (float*)carve((size_t)n * 128 * 4);
  float*          Psk    = (float*)carve((size_t)n * 128 * 4);
  float*          aS     = (float*)carve((size_t)n * HEADS * 4);
  float*          aD     = (float*)carve((size_t)n * HEADS * 4);
  unsigned short* FUS    = (unsigned short*)carve((size_t)n * 384 * 2);
  unsigned short* nbrb   = (unsigned short*)carve((size_t)n * 128 * 2);
  float*          sraw   = (float*)carve((size_t)n * 128 * 4);
  int* ideg   = (int*)carve((size_t)n * 4);
  int* offs   = (int*)carve(((size_t)n + 1) * 4);
  int* cursor = (int*)carve((size_t)n * 4);
  int* csrc   = (int*)carve((size_t)E * 4);

  hipMemsetAsync(ideg, 0, n * sizeof(int), stream);

  prep_w<<<(164480 + 255) / 256, 256, 0, stream>>>(
      gat_w, wq, wk, wv, wsk, bq, bk, bv, bsk, swl, swr, fus_w,
      Wcat_t, Bcat, sage_t, fus_t);
  convert_x<<<(n * 32 + 255) / 256, 256, 0, stream>>>(x, AG, n);

  // proj: [h q k v skip] = x @ Wcat + Bcat, routed epilogue
  gemm_mfma<0><<<dim3((n + 127) / 128, 10), 256, 0, stream>>>(
      (const __hip_bfloat16*)(AG + 384), 512, nullptr, 0,
      (const __hip_bfloat16*)Wcat_t, 128, Bcat,
      nullptr, 0, AG, Pqs, Psk, n, 640);

  att_ab<<<(n * HEADS + 255) / 256, 256, 0, stream>>>(AG, att_s, att_d, aS, aD, n);

  deg_hist<<<(E + 255) / 256, 256, 0, stream>>>(ei, ideg, E);
  scan_k<<<1, 256, 0, stream>>>(ideg, offs, cursor, n);
  scatter_k<<<(E + 255) / 256, 256, 0, stream>>>(ei, cursor, csrc, E);

  aggregate<<<(n + 3) / 4, 256, 0, stream>>>(AG, Pqs, Psk, aS, aD, offs, csrc,
                                             gat_b, FUS, nbrb, n);

  // sage_raw = [nbr | x] @ [swl; swr] + sbl
  gemm_mfma<1><<<dim3((n + 127) / 128, 2), 256, 0, stream>>>(
      (const __hip_bfloat16*)nbrb, 128, (const __hip_bfloat16*)(AG + 384), 512,
      (const __hip_bfloat16*)sage_t, 256, sbl,
      sraw, 128, nullptr, nullptr, nullptr, n, 128);
  l2norm_rows<<<(n + 3) / 4, 256, 0, stream>>>(sraw, FUS, n);

  // out = [gat | sage | tr] @ fus_w + fus_b, then LayerNorm in place
  gemm_mfma<1><<<dim3((n + 127) / 128, 2), 256, 0, stream>>>(
      (const __hip_bfloat16*)FUS, 384, nullptr, 0,
      (const __hip_bfloat16*)fus_t, 384, fus_b,
      out, 128, nullptr, nullptr, nullptr, n, 128);
  ln_k<<<(n + 3) / 4, 256, 0, stream>>>(out, ln_g, ln_b, n);
}

// Round 3
// 468.829 us; speedup vs baseline: 2.1000x; 1.4077x over previous
//
#include <hip/hip_runtime.h>
#include <hip/hip_bf16.h>
#include <math.h>

#define DIM 128
#define HEADS 8

typedef short short8 __attribute__((ext_vector_type(8)));
typedef float f32x4 __attribute__((ext_vector_type(4)));

#define GLD_LDS16(g, l) \
  __builtin_amdgcn_global_load_lds((const __attribute__((address_space(1))) void*)(g), \
                                   (__attribute__((address_space(3))) void*)(l), 16, 0, 0)

__device__ __forceinline__ float bf2f(unsigned short u) {
  union { unsigned int i; float f; } c; c.i = ((unsigned int)u) << 16; return c.f;
}
__device__ __forceinline__ unsigned short f2bf(float f) {
  __hip_bfloat16 h = __float2bfloat16(f);
  union { __hip_bfloat16 h; unsigned short u; } c; c.h = h; return c.u;
}
__device__ __forceinline__ float u_lo(unsigned int u) {
  union { unsigned int i; float f; } c; c.i = u << 16; return c.f;
}
__device__ __forceinline__ float u_hi(unsigned int u) {
  union { unsigned int i; float f; } c; c.i = u & 0xffff0000u; return c.f;
}

// ---------------- prep: transposed bf16 weights + Bcat --------------
__global__ void prep_w(const float* __restrict__ gw, const float* __restrict__ wq,
                       const float* __restrict__ wk, const float* __restrict__ wv,
                       const float* __restrict__ wsk,
                       const float* __restrict__ bq, const float* __restrict__ bk,
                       const float* __restrict__ bv, const float* __restrict__ bsk,
                       const float* __restrict__ swl, const float* __restrict__ swr,
                       const float* __restrict__ fw,
                       unsigned short* __restrict__ Wcat_t, float* __restrict__ Bcat,
                       unsigned short* __restrict__ sage_t, unsigned short* __restrict__ fus_t) {
  int i = blockIdx.x * 256 + threadIdx.x;
  if (i < 81920) {                      // Wcat_t[640][128]
    int c = i >> 7, k = i & 127;
    int s = c >> 7, j = c & 127;
    const float* w = (s == 0) ? gw : (s == 1) ? wq : (s == 2) ? wk : (s == 3) ? wv : wsk;
    Wcat_t[i] = f2bf(w[k * 128 + j]);
  } else if (i < 114688) {              // sage_t[128][256]
    int t = i - 81920;
    int j = t >> 8, k = t & 255;
    float v = (k < 128) ? swl[k * 128 + j] : swr[(k - 128) * 128 + j];
    sage_t[t] = f2bf(v);
  } else if (i < 163840) {              // fus_t[128][384]
    int t = i - 114688;
    int j = t / 384, k = t - j * 384;
    fus_t[t] = f2bf(fw[k * 128 + j]);
  } else if (i < 164480) {              // Bcat[640]
    int c = i - 163840;
    int s = c >> 7, j = c & 127;
    Bcat[c] = (s == 0) ? 0.f : (s == 1) ? bq[j] : (s == 2) ? bk[j] : (s == 3) ? bv[j] : bsk[j];
  }
}

// ---------------- x -> AG x-slab (bf16) -----------------------------
__global__ void convert_x(const float* __restrict__ x, unsigned short* __restrict__ AG, int n) {
  int i = blockIdx.x * 256 + threadIdx.x;
  if (i >= n * 32) return;
  int idx = i * 4;
  float4 v = *(const float4*)(x + idx);
  ushort4 u;
  u.x = f2bf(v.x); u.y = f2bf(v.y); u.z = f2bf(v.z); u.w = f2bf(v.w);
  *(ushort4*)(AG + (size_t)(idx >> 7) * 512 + 384 + (idx & 127)) = u;
}

// ---------------- bf16 MFMA GEMM ------------------------------------
template <int EPI>
__global__ __launch_bounds__(256) void gemm_mfma(
    const __hip_bfloat16* __restrict__ A0, int lda0,
    const __hip_bfloat16* __restrict__ A1, int lda1,
    const __hip_bfloat16* __restrict__ Bt, int K,
    const float* __restrict__ bias,
    float* __restrict__ outF, int ldo,
    unsigned short* __restrict__ AGo, float* __restrict__ Pq, float* __restrict__ Psk,
    int M, int N) {
  __shared__ char Asb[128 * 64];
  __shared__ char Bsb[64 * 64];
  int tid = threadIdx.x;
  int l = tid & 63, w = tid >> 6;
  int row0 = blockIdx.x * 128, col0 = blockIdx.y * 64;
  f32x4 acc[2][4] = {};

  for (int kt = 0; kt < K; kt += 32) {
    const __hip_bfloat16* Ap;
    int lda, kof;
    if (A1 != nullptr && kt >= 128) { Ap = A1; lda = lda1; kof = kt - 128; }
    else { Ap = A0; lda = lda0; kof = kt; }
#pragma unroll
    for (int it = 0; it < 2; ++it) {
      int c = it * 256 + tid;
      int r = c >> 2, cp = c & 3;
      int gp = cp ^ (r & 3);
      int gr = row0 + r; if (gr >= M) gr = M - 1;
      GLD_LDS16((const char*)(Ap + (size_t)gr * lda + kof) + gp * 16, Asb + c * 16);
    }
    {
      int c = tid;
      int r = c >> 2, cp = c & 3;
      int gp = cp ^ (r & 3);
      GLD_LDS16((const char*)(Bt + (size_t)(col0 + r) * K + kt) + gp * 16, Bsb + c * 16);
    }
    __syncthreads();
    int g = l >> 4, ri = l & 15;
    short8 af[2], bfr[4];
#pragma unroll
    for (int m = 0; m < 2; ++m) {
      int r = w * 32 + m * 16 + ri;
      af[m] = *(const short8*)(Asb + r * 64 + ((g ^ (r & 3)) * 16));
    }
#pragma unroll
    for (int c4 = 0; c4 < 4; ++c4) {
      int r = c4 * 16 + ri;
      bfr[c4] = *(const short8*)(Bsb + r * 64 + ((g ^ (r & 3)) * 16));
    }
#pragma unroll
    for (int m = 0; m < 2; ++m)
#pragma unroll
      for (int c4 = 0; c4 < 4; ++c4)
        acc[m][c4] = __builtin_amdgcn_mfma_f32_16x16x32_bf16(af[m], bfr[c4], acc[m][c4], 0, 0, 0);
    __syncthreads();
  }

  int g = l >> 4, ri = l & 15;
#pragma unroll
  for (int m = 0; m < 2; ++m) {
#pragma unroll
    for (int c4 = 0; c4 < 4; ++c4) {
#pragma unroll
      for (int j = 0; j < 4; ++j) {
        int row = row0 + w * 32 + m * 16 + g * 4 + j;
        if (row >= M) continue;
        int col = col0 + c4 * 16 + ri;
        float v = acc[m][c4][j] + bias[col];
        if (EPI == 0) {
          if (col < 128)       AGo[(size_t)row * 512 + col] = f2bf(v);
          else if (col < 256)  Pq[(size_t)row * 128 + (col - 128)] = v;
          else if (col < 512)  AGo[(size_t)row * 512 + (col - 128)] = f2bf(v);
          else                 Psk[(size_t)row * 128 + (col - 512)] = v;
        } else {
          outF[(size_t)row * ldo + col] = v;
        }
      }
    }
  }
}

// ---------------- a_src / a_dst -------------------------------------
__global__ void att_ab(const unsigned short* __restrict__ AG, const float* __restrict__ atts,
                       const float* __restrict__ attd, float* __restrict__ aS,
                       float* __restrict__ aD, int n) {
  int i = blockIdx.x * 256 + threadIdx.x;
  if (i >= n * HEADS) return;
  int node = i >> 3, hd = i & 7;
  const unsigned short* hrow = AG + (size_t)node * 512 + hd * 16;
  const float* s = atts + hd * 16;
  const float* d = attd + hd * 16;
  float s1 = 0.f, s2 = 0.f;
#pragma unroll
  for (int c = 0; c < 16; ++c) {
    float hv = bf2f(hrow[c]);
    s1 += hv * s[c];
    s2 += hv * d[c];
  }
  aS[i] = s1;
  aD[i] = s2;
}

// ---------------- CSR build (hierarchical scan) ---------------------
__global__ void deg_hist(const int* __restrict__ ei, int* __restrict__ deg, int E) {
  int e = blockIdx.x * 256 + threadIdx.x;
  if (e < E) atomicAdd(&deg[ei[E + e]], 1);
}

// block sums over 1024-elem segments
__global__ void bsum_k(const int* __restrict__ deg, int* __restrict__ bsum, int n) {
  int blk = blockIdx.x, t = threadIdx.x;
  int base = blk * 1024 + t * 4;
  int s = 0;
  if (base + 3 < n) {
    int4 d = *(const int4*)(deg + base);
    s = d.x + d.y + d.z + d.w;
  } else {
#pragma unroll
    for (int j = 0; j < 4; ++j) { int i = base + j; if (i < n) s += deg[i]; }
  }
  int lane = t & 63, wid = t >> 6;
  int x = s;
#pragma unroll
  for (int d = 1; d < 64; d <<= 1) { int y = __shfl_up(x, d); if (lane >= d) x += y; }
  __shared__ int wsum[4];
  if (lane == 63) wsum[wid] = x;
  __syncthreads();
  if (t == 0) bsum[blk] = wsum[0] + wsum[1] + wsum[2] + wsum[3];
}

// one-wave scan of block sums (any nb, 64 per pass)
__global__ void bscan_k(const int* __restrict__ bsum, int* __restrict__ bpref,
                        int* __restrict__ total_out, int nb) {
  int lane = threadIdx.x;
  int carry = 0;
  for (int base = 0; base < nb; base += 64) {
    int i = base + lane;
    int v = (i < nb) ? bsum[i] : 0;
    int x = v;
#pragma unroll
    for (int d = 1; d < 64; d <<= 1) { int y = __shfl_up(x, d); if (lane >= d) x += y; }
    if (i < nb) bpref[i] = carry + x - v;
    carry += __shfl(x, 63);
  }
  if (lane == 0) total_out[0] = carry;
}

// expand: offs[i] / cursor[i] = bpref[blk] + local exclusive
__global__ void offs_k(const int* __restrict__ deg, const int* __restrict__ bpref,
                       int* __restrict__ offs, int* __restrict__ cursor, int n) {
  int blk = blockIdx.x, t = threadIdx.x;
  int base = blk * 1024 + t * 4;
  int d0 = 0, d1 = 0, d2 = 0, d3 = 0;
  if (base + 3 < n) {
    int4 d = *(const int4*)(deg + base);
    d0 = d.x; d1 = d.y; d2 = d.z; d3 = d.w;
  } else {
    if (base + 0 < n) d0 = deg[base + 0];
    if (base + 1 < n) d1 = deg[base + 1];
    if (base + 2 < n) d2 = deg[base + 2];
    if (base + 3 < n) d3 = deg[base + 3];
  }
  int s = d0 + d1 + d2 + d3;
  int lane = t & 63, wid = t >> 6;
  int x = s;
#pragma unroll
  for (int d = 1; d < 64; d <<= 1) { int y = __shfl_up(x, d); if (lane >= d) x += y; }
  __shared__ int wsum[4];
  if (lane == 63) wsum[wid] = x;
  __syncthreads();
  int woff = 0;
  for (int ww = 0; ww < wid; ++ww) woff += wsum[ww];
  int excl = bpref[blk] + woff + x - s;
  int p0 = excl, p1 = excl + d0, p2 = p1 + d1, p3 = p2 + d2;
  if (base + 0 < n) { offs[base + 0] = p0; cursor[base + 0] = p0; }
  if (base + 1 < n) { offs[base + 1] = p1; cursor[base + 1] = p1; }
  if (base + 2 < n) { offs[base + 2] = p2; cursor[base + 2] = p2; }
  if (base + 3 < n) { offs[base + 3] = p3; cursor[base + 3] = p3; }
}

__global__ void scatter_k(const int* __restrict__ ei, int* __restrict__ cursor,
                          int* __restrict__ csrc, int E) {
  int e = blockIdx.x * 256 + threadIdx.x;
  if (e >= E) return;
  int src = ei[e], dst = ei[E + e];
  int pos = atomicAdd(&cursor[dst], 1);
  csrc[pos] = src;
}

// ---------------- per-node aggregation ------------------------------
// branchless online softmax; 4-edge batched gathers for MLP latency hiding
__global__ __launch_bounds__(256) void aggregate(
    const unsigned short* __restrict__ AG, const float* __restrict__ Pq,
    const float* __restrict__ Psk,
    const float* __restrict__ aS, const float* __restrict__ aD,
    const int* __restrict__ offs, const int* __restrict__ csrc,
    const float* __restrict__ gat_b,
    unsigned short* __restrict__ FUS, unsigned short* __restrict__ nbrb, int n) {
  int node = blockIdx.x * 4 + (threadIdx.x >> 6);
  if (node >= n) return;
  int lane = threadIdx.x & 63;
  int head = lane >> 3;
  const unsigned short* An = AG + (size_t)node * 512;
  float2 qv = *(const float2*)(Pq + (size_t)node * 128 + 2 * lane);
  float adst = aD[node * HEADS + head];

  float lg0 = aS[node * HEADS + head] + adst;
  lg0 = fmaxf(lg0, 0.2f * lg0);
  float m_g = lg0, l_g = 1.f;
  unsigned int hu0 = *(const unsigned int*)(An + 2 * lane);
  float2 acc_g = { u_lo(hu0), u_hi(hu0) };

  float m_t = -1e30f, l_t = 0.f;
  float2 acc_t = {0.f, 0.f};
  float2 acc_s = {0.f, 0.f};

  int e0 = offs[node], e1 = offs[node + 1];

#define EDGE_UPDATE(HU, KU, VU, XU, AV)                                  \
  {                                                                      \
    float lg = (AV) + adst;                                              \
    lg = fmaxf(lg, 0.2f * lg);                                           \
    float mg = fmaxf(m_g, lg);                                           \
    float scg = __expf(m_g - mg), wg = __expf(lg - mg);                  \
    acc_g.x = acc_g.x * scg + wg * u_lo(HU);                             \
    acc_g.y = acc_g.y * scg + wg * u_hi(HU);                             \
    l_g = l_g * scg + wg; m_g = mg;                                      \
    float part = qv.x * u_lo(KU) + qv.y * u_hi(KU);                      \
    part += __shfl_xor(part, 1);                                         \
    part += __shfl_xor(part, 2);                                         \
    part += __shfl_xor(part, 4);                                         \
    float tl = part * 0.25f;                                             \
    float mt = fmaxf(m_t, tl);                                           \
    float sct = __expf(m_t - mt), wt = __expf(tl - mt);                  \
    acc_t.x = acc_t.x * sct + wt * u_lo(VU);                             \
    acc_t.y = acc_t.y * sct + wt * u_hi(VU);                             \
    l_t = l_t * sct + wt; m_t = mt;                                      \
    acc_s.x += u_lo(XU);                                                 \
    acc_s.y += u_hi(XU);                                                 \
  }

  int e = e0;
  for (; e + 4 <= e1; e += 4) {
    int si[4];
#pragma unroll
    for (int u = 0; u < 4; ++u) si[u] = csrc[e + u];
    unsigned int hu[4], ku[4], vu[4], xu[4];
    float av[4];
#pragma unroll
    for (int u = 0; u < 4; ++u) {
      const unsigned short* As = AG + (size_t)si[u] * 512;
      hu[u] = *(const unsigned int*)(As + 2 * lane);
      ku[u] = *(const unsigned int*)(As + 128 + 2 * lane);
      vu[u] = *(const unsigned int*)(As + 256 + 2 * lane);
      xu[u] = *(const unsigned int*)(As + 384 + 2 * lane);
      av[u] = aS[si[u] * HEADS + head];
    }
#pragma unroll
    for (int u = 0; u < 4; ++u) EDGE_UPDATE(hu[u], ku[u], vu[u], xu[u], av[u]);
  }
  for (; e < e1; ++e) {
    int s = csrc[e];
    const unsigned short* As = AG + (size_t)s * 512;
    unsigned int hu = *(const unsigned int*)(As + 2 * lane);
    unsigned int ku = *(const unsigned int*)(As + 128 + 2 * lane);
    unsigned int vu = *(const unsigned int*)(As + 256 + 2 * lane);
    unsigned int xu = *(const unsigned int*)(As + 384 + 2 * lane);
    float av = aS[s * HEADS + head];
    EDGE_UPDATE(hu, ku, vu, xu, av);
  }
#undef EDGE_UPDATE

  // finalize: gat -> FUS[:,0:128], tr -> FUS[:,256:384], nbr -> nbrb
  float gx = acc_g.x / l_g + gat_b[2 * lane];
  float gy = acc_g.y / l_g + gat_b[2 * lane + 1];
  ushort2 go = { f2bf(gx), f2bf(gy) };
  *(ushort2*)(FUS + (size_t)node * 384 + 2 * lane) = go;

  float2 skip = *(const float2*)(Psk + (size_t)node * 128 + 2 * lane);
  float tx, ty;
  if (l_t > 0.f) {
    tx = acc_t.x / l_t + skip.x;
    ty = acc_t.y / l_t + skip.y;
  } else { tx = skip.x; ty = skip.y; }
  ushort2 to = { f2bf(tx), f2bf(ty) };
  *(ushort2*)(FUS + (size_t)node * 384 + 256 + 2 * lane) = to;

  float dg = fmaxf((float)(e1 - e0), 1.f);
  float inv = 1.f / dg;
  ushort2 nb = { f2bf(acc_s.x * inv), f2bf(acc_s.y * inv) };
  *(ushort2*)(nbrb + (size_t)node * 128 + 2 * lane) = nb;
}

// ---------------- row L2 normalize (sage) -> FUS mid slab -----------
__global__ void l2norm_rows(const float* __restrict__ sraw, unsigned short* __restrict__ FUS, int n) {
  int node = blockIdx.x * 4 + (threadIdx.x >> 6);
  if (node >= n) return;
  int lane = threadIdx.x & 63;
  float2 v = *(const float2*)(sraw + (size_t)node * 128 + 2 * lane);
  float ss = v.x * v.x + v.y * v.y;
#pragma unroll
  for (int d = 1; d < 64; d <<= 1) ss += __shfl_xor(ss, d);
  float nrm = fmaxf(sqrtf(ss), 1e-12f);
  float inv = 1.f / nrm;
  ushort2 o = { f2bf(v.x * inv), f2bf(v.y * inv) };
  *(ushort2*)(FUS + (size_t)node * 384 + 128 + 2 * lane) = o;
}

// ---------------- in-place LayerNorm on d_out -----------------------
__global__ void ln_k(float* __restrict__ y, const float* __restrict__ g,
                     const float* __restrict__ b, int n) {
  int node = blockIdx.x * 4 + (threadIdx.x >> 6);
  if (node >= n) return;
  int lane = threadIdx.x & 63;
  float2* row = (float2*)(y + (size_t)node * DIM);
  float2 v = row[lane];
  float s = v.x + v.y;
#pragma unroll
  for (int d = 1; d < 64; d <<= 1) s += __shfl_xor(s, d);
  float mu = s * (1.f / 128.f);
  float dx = v.x - mu, dy = v.y - mu;
  float ss = dx * dx + dy * dy;
#pragma unroll
  for (int d = 1; d < 64; d <<= 1) ss += __shfl_xor(ss, d);
  float rstd = 1.f / sqrtf(ss * (1.f / 128.f) + 1e-5f);
  float2 gg = ((const float2*)g)[lane];
  float2 bb = ((const float2*)b)[lane];
  float2 o;
  o.x = dx * rstd * gg.x + bb.x;
  o.y = dy * rstd * gg.y + bb.y;
  row[lane] = o;
}

extern "C" void kernel_launch(void* const* d_in, const int* in_sizes, int n_in,
                              void* d_out, int out_size, void* d_ws, size_t ws_size,
                              hipStream_t stream) {
  const float* x      = (const float*)d_in[0];
  const int*   ei     = (const int*)d_in[1];
  const float* gat_w  = (const float*)d_in[2];
  const float* att_s  = (const float*)d_in[3];
  const float* att_d  = (const float*)d_in[4];
  const float* gat_b  = (const float*)d_in[5];
  const float* swl    = (const float*)d_in[6];
  const float* sbl    = (const float*)d_in[7];
  const float* swr    = (const float*)d_in[8];
  const float* wq     = (const float*)d_in[9];
  const float* bq     = (const float*)d_in[10];
  const float* wk     = (const float*)d_in[11];
  const float* bk     = (const float*)d_in[12];
  const float* wv     = (const float*)d_in[13];
  const float* bv     = (const float*)d_in[14];
  const float* wsk    = (const float*)d_in[15];
  const float* bsk    = (const float*)d_in[16];
  const float* fus_w  = (const float*)d_in[17];
  const float* fus_b  = (const float*)d_in[18];
  const float* ln_g   = (const float*)d_in[19];
  const float* ln_b   = (const float*)d_in[20];
  float* out = (float*)d_out;

  const int n = in_sizes[0] / DIM;  // 50000
  const int E = in_sizes[1] / 2;    // 800000

  char* wsb = (char*)d_ws;
  size_t o = 0;
  auto carve = [&](size_t bytes) { char* p = wsb + o; o += (bytes + 255) & ~(size_t)255; return p; };
  unsigned short* Wcat_t = (unsigned short*)carve(640 * 128 * 2);
  float*          Bcat   = (float*)carve(640 * 4);
  unsigned short* sage_t = (unsigned short*)carve(128 * 256 * 2);
  unsigned short* fus_t  = (unsigned short*)carve(128 * 384 * 2);
  unsigned short* AG     = (unsigned short*)carve((size_t)n * 512 * 2);
  float*          Pqs    = (float*)carve((size_t)n * 128 * 4);
  float*          Psk    = (float*)carve((size_t)n * 128 * 4);
  float*          aS     = (float*)carve((size_t)n * HEADS * 4);
  float*          aD     = (float*)carve((size_t)n * HEADS * 4);
  unsigned short* FUS    = (unsigned short*)carve((size_t)n * 384 * 2);
  unsigned short* nbrb   = (unsigned short*)carve((size_t)n * 128 * 2);
  float*          sraw   = (float*)carve((size_t)n * 128 * 4);
  int* ideg   = (int*)carve((size_t)n * 4);
  int* offs   = (int*)carve(((size_t)n + 1) * 4);
  int* cursor = (int*)carve((size_t)n * 4);
  int* csrc   = (int*)carve((size_t)E * 4);
  const int NB = (n + 1023) / 1024;
  int* bsum   = (int*)carve((size_t)NB * 4);
  int* bpref  = (int*)carve((size_t)NB * 4);

  hipMemsetAsync(ideg, 0, n * sizeof(int), stream);

  prep_w<<<(164480 + 255) / 256, 256, 0, stream>>>(
      gat_w, wq, wk, wv, wsk, bq, bk, bv, bsk, swl, swr, fus_w,
      Wcat_t, Bcat, sage_t, fus_t);
  convert_x<<<(n * 32 + 255) / 256, 256, 0, stream>>>(x, AG, n);

  // proj: [h q k v skip] = x @ Wcat + Bcat, routed epilogue
  gemm_mfma<0><<<dim3((n + 127) / 128, 10), 256, 0, stream>>>(
      (const __hip_bfloat16*)(AG + 384), 512, nullptr, 0,
      (const __hip_bfloat16*)Wcat_t, 128, Bcat,
      nullptr, 0, AG, Pqs, Psk, n, 640);

  att_ab<<<(n * HEADS + 255) / 256, 256, 0, stream>>>(AG, att_s, att_d, aS, aD, n);

  deg_hist<<<(E + 255) / 256, 256, 0, stream>>>(ei, ideg, E);
  bsum_k<<<NB, 256, 0, stream>>>(ideg, bsum, n);
  bscan_k<<<1, 64, 0, stream>>>(bsum, bpref, offs + n, NB);
  offs_k<<<NB, 256, 0, stream>>>(ideg, bpref, offs, cursor, n);
  scatter_k<<<(E + 255) / 256, 256, 0, stream>>>(ei, cursor, csrc, E);

  aggregate<<<(n + 3) / 4, 256, 0, stream>>>(AG, Pqs, Psk, aS, aD, offs, csrc,
                                             gat_b, FUS, nbrb, n);

  // sage_raw = [nbr | x] @ [swl; swr] + sbl
  gemm_mfma<1><<<dim3((n + 127) / 128, 2), 256, 0, stream>>>(
      (const __hip_bfloat16*)nbrb, 128, (const __hip_bfloat16*)(AG + 384), 512,
      (const __hip_bfloat16*)sage_t, 256, sbl,
      sraw, 128, nullptr, nullptr, nullptr, n, 128);
  l2norm_rows<<<(n + 3) / 4, 256, 0, stream>>>(sraw, FUS, n);

  // out = [gat | sage | tr] @ fus_w + fus_b, then LayerNorm in place
  gemm_mfma<1><<<dim3((n + 127) / 128, 2), 256, 0, stream>>>(
      (const __hip_bfloat16*)FUS, 384, nullptr, 0,
      (const __hip_bfloat16*)fus_t, 384, fus_b,
      out, 128, nullptr, nullptr, nullptr, n, 128);
  ln_k<<<(n + 3) / 4, 256, 0, stream>>>(out, ln_g, ln_b, n);
}

// Round 5
// 422.147 us; speedup vs baseline: 2.3322x; 1.1106x over previous
//
#include <hip/hip_runtime.h>
#include <hip/hip_bf16.h>
#include <math.h>

#define DIM 128
#define HEADS 8

typedef short short8 __attribute__((ext_vector_type(8)));
typedef float f32x4 __attribute__((ext_vector_type(4)));

#define GLD_LDS16(g, l) \
  __builtin_amdgcn_global_load_lds((const __attribute__((address_space(1))) void*)(g), \
                                   (__attribute__((address_space(3))) void*)(l), 16, 0, 0)

__device__ __forceinline__ float bf2f(unsigned short u) {
  union { unsigned int i; float f; } c; c.i = ((unsigned int)u) << 16; return c.f;
}
__device__ __forceinline__ unsigned short f2bf(float f) {
  __hip_bfloat16 h = __float2bfloat16(f);
  union { __hip_bfloat16 h; unsigned short u; } c; c.h = h; return c.u;
}
__device__ __forceinline__ float u_lo(unsigned int u) {
  union { unsigned int i; float f; } c; c.i = u << 16; return c.f;
}
__device__ __forceinline__ float u_hi(unsigned int u) {
  union { unsigned int i; float f; } c; c.i = u & 0xffff0000u; return c.f;
}

// ---------------- prep: transposed bf16 weights + Bcat --------------
__global__ void prep_w(const float* __restrict__ gw, const float* __restrict__ wq,
                       const float* __restrict__ wk, const float* __restrict__ wv,
                       const float* __restrict__ wsk,
                       const float* __restrict__ bq, const float* __restrict__ bk,
                       const float* __restrict__ bv, const float* __restrict__ bsk,
                       const float* __restrict__ swl, const float* __restrict__ swr,
                       const float* __restrict__ fw,
                       unsigned short* __restrict__ Wcat_t, float* __restrict__ Bcat,
                       unsigned short* __restrict__ sage_t, unsigned short* __restrict__ fus_t) {
  int i = blockIdx.x * 256 + threadIdx.x;
  if (i < 81920) {                      // Wcat_t[640][128]
    int c = i >> 7, k = i & 127;
    int s = c >> 7, j = c & 127;
    const float* w = (s == 0) ? gw : (s == 1) ? wq : (s == 2) ? wk : (s == 3) ? wv : wsk;
    Wcat_t[i] = f2bf(w[k * 128 + j]);
  } else if (i < 114688) {              // sage_t[128][256]
    int t = i - 81920;
    int j = t >> 8, k = t & 255;
    float v = (k < 128) ? swl[k * 128 + j] : swr[(k - 128) * 128 + j];
    sage_t[t] = f2bf(v);
  } else if (i < 163840) {              // fus_t[128][384]
    int t = i - 114688;
    int j = t / 384, k = t - j * 384;
    fus_t[t] = f2bf(fw[k * 128 + j]);
  } else if (i < 164480) {              // Bcat[640]
    int c = i - 163840;
    int s = c >> 7, j = c & 127;
    Bcat[c] = (s == 0) ? 0.f : (s == 1) ? bq[j] : (s == 2) ? bk[j] : (s == 3) ? bv[j] : bsk[j];
  }
}

// ---------------- x -> AG x-slab (bf16) -----------------------------
__global__ void convert_x(const float* __restrict__ x, unsigned short* __restrict__ AG, int n) {
  int i = blockIdx.x * 256 + threadIdx.x;
  if (i >= n * 32) return;
  int idx = i * 4;
  float4 v = *(const float4*)(x + idx);
  ushort4 u;
  u.x = f2bf(v.x); u.y = f2bf(v.y); u.z = f2bf(v.z); u.w = f2bf(v.w);
  *(ushort4*)(AG + (size_t)(idx >> 7) * 512 + 384 + (idx & 127)) = u;
}

// ---------------- bf16 MFMA GEMM, tile 128x128, fused epilogues ------
// EPI 0: proj (grid.y=0..4 -> h+aS/aD, q, k, v, skip)
// EPI 1: sage (+bias, L2-normalize row, write bf16 to FUS[:,128:256))
// EPI 2: fusion (+bias, LayerNorm row, write f32 out)
template <int EPI>
__global__ __launch_bounds__(256) void gemm128(
    const __hip_bfloat16* __restrict__ A0, int lda0,
    const __hip_bfloat16* __restrict__ A1, int lda1,
    const __hip_bfloat16* __restrict__ Bt, int K,
    const float* __restrict__ bias,
    unsigned short* __restrict__ AGo, float* __restrict__ Pq, float* __restrict__ Psk,
    float* __restrict__ aSo, float* __restrict__ aDo,
    const float* __restrict__ atts, const float* __restrict__ attd,
    unsigned short* __restrict__ FUSo, float* __restrict__ outF,
    const float* __restrict__ lng, const float* __restrict__ lnb,
    int M) {
  __shared__ char Asb[128 * 64];   // 128 rows x 32 bf16
  __shared__ char Bsb[128 * 64];   // 128 cols x 32 bf16
  int tid = threadIdx.x;
  int l = tid & 63, w = tid >> 6;
  int row0 = blockIdx.x * 128, col0 = blockIdx.y * 128;
  f32x4 acc[2][8] = {};

  for (int kt = 0; kt < K; kt += 32) {
    const __hip_bfloat16* Ap;
    int lda, kof;
    if (A1 != nullptr && kt >= 128) { Ap = A1; lda = lda1; kof = kt - 128; }
    else { Ap = A0; lda = lda0; kof = kt; }
#pragma unroll
    for (int it = 0; it < 2; ++it) {   // A: 512 chunks
      int c = it * 256 + tid;
      int r = c >> 2, cp = c & 3;
      int gp = cp ^ (r & 3);
      int gr = row0 + r; if (gr >= M) gr = M - 1;
      GLD_LDS16((const char*)(Ap + (size_t)gr * lda + kof) + gp * 16, Asb + c * 16);
    }
#pragma unroll
    for (int it = 0; it < 2; ++it) {   // B: 512 chunks
      int c = it * 256 + tid;
      int r = c >> 2, cp = c & 3;
      int gp = cp ^ (r & 3);
      GLD_LDS16((const char*)(Bt + (size_t)(col0 + r) * K + kt) + gp * 16, Bsb + c * 16);
    }
    __syncthreads();
    int g = l >> 4, ri = l & 15;
    short8 af[2], bfr[8];
#pragma unroll
    for (int m = 0; m < 2; ++m) {
      int r = w * 32 + m * 16 + ri;
      af[m] = *(const short8*)(Asb + r * 64 + ((g ^ (r & 3)) * 16));
    }
#pragma unroll
    for (int c4 = 0; c4 < 8; ++c4) {
      int r = c4 * 16 + ri;
      bfr[c4] = *(const short8*)(Bsb + r * 64 + ((g ^ (r & 3)) * 16));
    }
#pragma unroll
    for (int m = 0; m < 2; ++m)
#pragma unroll
      for (int c4 = 0; c4 < 8; ++c4)
        acc[m][c4] = __builtin_amdgcn_mfma_f32_16x16x32_bf16(af[m], bfr[c4], acc[m][c4], 0, 0, 0);
    __syncthreads();
  }

  int g = l >> 4, ri = l & 15;
  float bias_r[8];
#pragma unroll
  for (int c4 = 0; c4 < 8; ++c4) bias_r[c4] = bias[col0 + c4 * 16 + ri];

  if (EPI == 0) {
    int y = col0 >> 7;  // 0..4
    if (y == 0) {
      float as_w[8], ad_w[8];
#pragma unroll
      for (int c4 = 0; c4 < 8; ++c4) { as_w[c4] = atts[c4 * 16 + ri]; ad_w[c4] = attd[c4 * 16 + ri]; }
#pragma unroll
      for (int m = 0; m < 2; ++m) {
#pragma unroll
        for (int j = 0; j < 4; ++j) {
          int row = row0 + w * 32 + m * 16 + g * 4 + j;
          bool ok = (row < M);
#pragma unroll
          for (int c4 = 0; c4 < 8; ++c4) {
            float v = acc[m][c4][j];
            if (ok) AGo[(size_t)row * 512 + c4 * 16 + ri] = f2bf(v);
            float p1 = v * as_w[c4], p2 = v * ad_w[c4];
            p1 += __shfl_xor(p1, 1); p1 += __shfl_xor(p1, 2);
            p1 += __shfl_xor(p1, 4); p1 += __shfl_xor(p1, 8);
            p2 += __shfl_xor(p2, 1); p2 += __shfl_xor(p2, 2);
            p2 += __shfl_xor(p2, 4); p2 += __shfl_xor(p2, 8);
            if (ok && ri == 0) { aSo[row * HEADS + c4] = p1; aDo[row * HEADS + c4] = p2; }
          }
        }
      }
    } else {
#pragma unroll
      for (int m = 0; m < 2; ++m) {
#pragma unroll
        for (int j = 0; j < 4; ++j) {
          int row = row0 + w * 32 + m * 16 + g * 4 + j;
          if (row >= M) continue;
#pragma unroll
          for (int c4 = 0; c4 < 8; ++c4) {
            int c = c4 * 16 + ri;
            float v = acc[m][c4][j] + bias_r[c4];
            if (y == 1)      Pq[(size_t)row * 128 + c] = v;
            else if (y == 2) AGo[(size_t)row * 512 + 128 + c] = f2bf(v);
            else if (y == 3) AGo[(size_t)row * 512 + 256 + c] = f2bf(v);
            else             Psk[(size_t)row * 128 + c] = v;
          }
        }
      }
    }
  } else {
    // full 128-col row lives in this block: per-(m,j) row reduce over c4 + 16 lanes
#pragma unroll
    for (int m = 0; m < 2; ++m) {
#pragma unroll
      for (int j = 0; j < 4; ++j) {
        int row = row0 + w * 32 + m * 16 + g * 4 + j;
        bool ok = (row < M);
        float v[8];
        float s = 0.f;
#pragma unroll
        for (int c4 = 0; c4 < 8; ++c4) {
          v[c4] = acc[m][c4][j] + bias_r[c4];
          if (EPI == 1) s += v[c4] * v[c4];
          else          s += v[c4];
        }
        s += __shfl_xor(s, 1); s += __shfl_xor(s, 2);
        s += __shfl_xor(s, 4); s += __shfl_xor(s, 8);
        if (EPI == 1) {
          float inv = 1.f / fmaxf(sqrtf(s), 1e-12f);
          if (ok) {
#pragma unroll
            for (int c4 = 0; c4 < 8; ++c4)
              FUSo[(size_t)row * 384 + 128 + c4 * 16 + ri] = f2bf(v[c4] * inv);
          }
        } else {
          float mu = s * (1.f / 128.f);
          float ss = 0.f;
#pragma unroll
          for (int c4 = 0; c4 < 8; ++c4) { float d = v[c4] - mu; ss += d * d; }
          ss += __shfl_xor(ss, 1); ss += __shfl_xor(ss, 2);
          ss += __shfl_xor(ss, 4); ss += __shfl_xor(ss, 8);
          float rstd = 1.f / sqrtf(ss * (1.f / 128.f) + 1e-5f);
          if (ok) {
#pragma unroll
            for (int c4 = 0; c4 < 8; ++c4) {
              int c = c4 * 16 + ri;
              outF[(size_t)row * 128 + c] = (v[c4] - mu) * rstd * lng[c] + lnb[c];
            }
          }
        }
      }
    }
  }
}

// ---------------- CSR build (hierarchical scan) ---------------------
__global__ void deg_hist(const int* __restrict__ ei, int* __restrict__ deg, int E) {
  int e = blockIdx.x * 256 + threadIdx.x;
  if (e < E) atomicAdd(&deg[ei[E + e]], 1);
}

__global__ void bsum_k(const int* __restrict__ deg, int* __restrict__ bsum, int n) {
  int blk = blockIdx.x, t = threadIdx.x;
  int base = blk * 1024 + t * 4;
  int s = 0;
  if (base + 3 < n) {
    int4 d = *(const int4*)(deg + base);
    s = d.x + d.y + d.z + d.w;
  } else {
#pragma unroll
    for (int j = 0; j < 4; ++j) { int i = base + j; if (i < n) s += deg[i]; }
  }
  int lane = t & 63, wid = t >> 6;
  int x = s;
#pragma unroll
  for (int d = 1; d < 64; d <<= 1) { int y = __shfl_up(x, d); if (lane >= d) x += y; }
  __shared__ int wsum[4];
  if (lane == 63) wsum[wid] = x;
  __syncthreads();
  if (t == 0) bsum[blk] = wsum[0] + wsum[1] + wsum[2] + wsum[3];
}

__global__ void bscan_k(const int* __restrict__ bsum, int* __restrict__ bpref,
                        int* __restrict__ total_out, int nb) {
  int lane = threadIdx.x;
  int carry = 0;
  for (int base = 0; base < nb; base += 64) {
    int i = base + lane;
    int v = (i < nb) ? bsum[i] : 0;
    int x = v;
#pragma unroll
    for (int d = 1; d < 64; d <<= 1) { int y = __shfl_up(x, d); if (lane >= d) x += y; }
    if (i < nb) bpref[i] = carry + x - v;
    carry += __shfl(x, 63);
  }
  if (lane == 0) total_out[0] = carry;
}

__global__ void offs_k(const int* __restrict__ deg, const int* __restrict__ bpref,
                       int* __restrict__ offs, int* __restrict__ cursor, int n) {
  int blk = blockIdx.x, t = threadIdx.x;
  int base = blk * 1024 + t * 4;
  int d0 = 0, d1 = 0, d2 = 0, d3 = 0;
  if (base + 3 < n) {
    int4 d = *(const int4*)(deg + base);
    d0 = d.x; d1 = d.y; d2 = d.z; d3 = d.w;
  } else {
    if (base + 0 < n) d0 = deg[base + 0];
    if (base + 1 < n) d1 = deg[base + 1];
    if (base + 2 < n) d2 = deg[base + 2];
    if (base + 3 < n) d3 = deg[base + 3];
  }
  int s = d0 + d1 + d2 + d3;
  int lane = t & 63, wid = t >> 6;
  int x = s;
#pragma unroll
  for (int d = 1; d < 64; d <<= 1) { int y = __shfl_up(x, d); if (lane >= d) x += y; }
  __shared__ int wsum[4];
  if (lane == 63) wsum[wid] = x;
  __syncthreads();
  int woff = 0;
  for (int ww = 0; ww < wid; ++ww) woff += wsum[ww];
  int excl = bpref[blk] + woff + x - s;
  int p0 = excl, p1 = excl + d0, p2 = p1 + d1, p3 = p2 + d2;
  if (base + 0 < n) { offs[base + 0] = p0; cursor[base + 0] = p0; }
  if (base + 1 < n) { offs[base + 1] = p1; cursor[base + 1] = p1; }
  if (base + 2 < n) { offs[base + 2] = p2; cursor[base + 2] = p2; }
  if (base + 3 < n) { offs[base + 3] = p3; cursor[base + 3] = p3; }
}

__global__ void scatter_k(const int* __restrict__ ei, int* __restrict__ cursor,
                          int* __restrict__ csrc, int E) {
  int e = blockIdx.x * 256 + threadIdx.x;
  if (e >= E) return;
  int src = ei[e], dst = ei[E + e];
  int pos = atomicAdd(&cursor[dst], 1);
  csrc[pos] = src;
}

// ---------------- per-node aggregation ------------------------------
// branchless online softmax; 8-edge batched gathers (ILP latency hiding)
__global__ __launch_bounds__(256) void aggregate(
    const unsigned short* __restrict__ AG, const float* __restrict__ Pq,
    const float* __restrict__ Psk,
    const float* __restrict__ aS, const float* __restrict__ aD,
    const int* __restrict__ offs, const int* __restrict__ csrc,
    const float* __restrict__ gat_b,
    unsigned short* __restrict__ FUS, unsigned short* __restrict__ nbrb, int n) {
  int node = blockIdx.x * 4 + (threadIdx.x >> 6);
  if (node >= n) return;
  int lane = threadIdx.x & 63;
  int head = lane >> 3;
  const unsigned short* An = AG + (size_t)node * 512;
  float2 qv = *(const float2*)(Pq + (size_t)node * 128 + 2 * lane);
  float adst = aD[node * HEADS + head];

  float lg0 = aS[node * HEADS + head] + adst;
  lg0 = fmaxf(lg0, 0.2f * lg0);
  float m_g = lg0, l_g = 1.f;
  unsigned int hu0 = *(const unsigned int*)(An + 2 * lane);
  float2 acc_g = { u_lo(hu0), u_hi(hu0) };

  float m_t = -1e30f, l_t = 0.f;
  float2 acc_t = {0.f, 0.f};
  float2 acc_s = {0.f, 0.f};

  int e0 = offs[node], e1 = offs[node + 1];

#define EDGE_UPDATE(HU, KU, VU, XU, AV)                                  \
  {                                                                      \
    float lg = (AV) + adst;                                              \
    lg = fmaxf(lg, 0.2f * lg);                                           \
    float mg = fmaxf(m_g, lg);                                           \
    float scg = __expf(m_g - mg), wg = __expf(lg - mg);                  \
    acc_g.x = acc_g.x * scg + wg * u_lo(HU);                             \
    acc_g.y = acc_g.y * scg + wg * u_hi(HU);                             \
    l_g = l_g * scg + wg; m_g = mg;                                      \
    float part = qv.x * u_lo(KU) + qv.y * u_hi(KU);                      \
    part += __shfl_xor(part, 1);                                         \
    part += __shfl_xor(part, 2);                                         \
    part += __shfl_xor(part, 4);                                         \
    float tl = part * 0.25f;                                             \
    float mt = fmaxf(m_t, tl);                                           \
    float sct = __expf(m_t - mt), wt = __expf(tl - mt);                  \
    acc_t.x = acc_t.x * sct + wt * u_lo(VU);                             \
    acc_t.y = acc_t.y * sct + wt * u_hi(VU);                             \
    l_t = l_t * sct + wt; m_t = mt;                                      \
    acc_s.x += u_lo(XU);                                                 \
    acc_s.y += u_hi(XU);                                                 \
  }

#define LOAD_EDGE(u, si_a, hu_a, ku_a, vu_a, xu_a, av_a)                 \
  {                                                                      \
    const unsigned short* As = AG + (size_t)si_a[u] * 512;               \
    hu_a[u] = *(const unsigned int*)(As + 2 * lane);                     \
    ku_a[u] = *(const unsigned int*)(As + 128 + 2 * lane);               \
    vu_a[u] = *(const unsigned int*)(As + 256 + 2 * lane);               \
    xu_a[u] = *(const unsigned int*)(As + 384 + 2 * lane);               \
    av_a[u] = aS[si_a[u] * HEADS + head];                                \
  }

  int e = e0;
  for (; e + 8 <= e1; e += 8) {
    int si[8];
#pragma unroll
    for (int u = 0; u < 8; ++u) si[u] = csrc[e + u];
    unsigned int hu[8], ku[8], vu[8], xu[8];
    float av[8];
#pragma unroll
    for (int u = 0; u < 8; ++u) LOAD_EDGE(u, si, hu, ku, vu, xu, av);
#pragma unroll
    for (int u = 0; u < 8; ++u) EDGE_UPDATE(hu[u], ku[u], vu[u], xu[u], av[u]);
  }
  if (e + 4 <= e1) {
    int si[4];
#pragma unroll
    for (int u = 0; u < 4; ++u) si[u] = csrc[e + u];
    unsigned int hu[4], ku[4], vu[4], xu[4];
    float av[4];
#pragma unroll
    for (int u = 0; u < 4; ++u) LOAD_EDGE(u, si, hu, ku, vu, xu, av);
#pragma unroll
    for (int u = 0; u < 4; ++u) EDGE_UPDATE(hu[u], ku[u], vu[u], xu[u], av[u]);
    e += 4;
  }
  for (; e < e1; ++e) {
    int s = csrc[e];
    const unsigned short* As = AG + (size_t)s * 512;
    unsigned int hu = *(const unsigned int*)(As + 2 * lane);
    unsigned int ku = *(const unsigned int*)(As + 128 + 2 * lane);
    unsigned int vu = *(const unsigned int*)(As + 256 + 2 * lane);
    unsigned int xu = *(const unsigned int*)(As + 384 + 2 * lane);
    float av = aS[s * HEADS + head];
    EDGE_UPDATE(hu, ku, vu, xu, av);
  }
#undef EDGE_UPDATE
#undef LOAD_EDGE

  float gx = acc_g.x / l_g + gat_b[2 * lane];
  float gy = acc_g.y / l_g + gat_b[2 * lane + 1];
  ushort2 go = { f2bf(gx), f2bf(gy) };
  *(ushort2*)(FUS + (size_t)node * 384 + 2 * lane) = go;

  float2 skip = *(const float2*)(Psk + (size_t)node * 128 + 2 * lane);
  float tx, ty;
  if (l_t > 0.f) {
    tx = acc_t.x / l_t + skip.x;
    ty = acc_t.y / l_t + skip.y;
  } else { tx = skip.x; ty = skip.y; }
  ushort2 to = { f2bf(tx), f2bf(ty) };
  *(ushort2*)(FUS + (size_t)node * 384 + 256 + 2 * lane) = to;

  float dg = fmaxf((float)(e1 - e0), 1.f);
  float inv = 1.f / dg;
  ushort2 nb = { f2bf(acc_s.x * inv), f2bf(acc_s.y * inv) };
  *(ushort2*)(nbrb + (size_t)node * 128 + 2 * lane) = nb;
}

extern "C" void kernel_launch(void* const* d_in, const int* in_sizes, int n_in,
                              void* d_out, int out_size, void* d_ws, size_t ws_size,
                              hipStream_t stream) {
  const float* x      = (const float*)d_in[0];
  const int*   ei     = (const int*)d_in[1];
  const float* gat_w  = (const float*)d_in[2];
  const float* att_s  = (const float*)d_in[3];
  const float* att_d  = (const float*)d_in[4];
  const float* gat_b  = (const float*)d_in[5];
  const float* swl    = (const float*)d_in[6];
  const float* sbl    = (const float*)d_in[7];
  const float* swr    = (const float*)d_in[8];
  const float* wq     = (const float*)d_in[9];
  const float* bq     = (const float*)d_in[10];
  const float* wk     = (const float*)d_in[11];
  const float* bk     = (const float*)d_in[12];
  const float* wv     = (const float*)d_in[13];
  const float* bv     = (const float*)d_in[14];
  const float* wsk    = (const float*)d_in[15];
  const float* bsk    = (const float*)d_in[16];
  const float* fus_w  = (const float*)d_in[17];
  const float* fus_b  = (const float*)d_in[18];
  const float* ln_g   = (const float*)d_in[19];
  const float* ln_b   = (const float*)d_in[20];
  float* out = (float*)d_out;

  const int n = in_sizes[0] / DIM;  // 50000
  const int E = in_sizes[1] / 2;    // 800000

  char* wsb = (char*)d_ws;
  size_t o = 0;
  auto carve = [&](size_t bytes) { char* p = wsb + o; o += (bytes + 255) & ~(size_t)255; return p; };
  unsigned short* Wcat_t = (unsigned short*)carve(640 * 128 * 2);
  float*          Bcat   = (float*)carve(640 * 4);
  unsigned short* sage_t = (unsigned short*)carve(128 * 256 * 2);
  unsigned short* fus_t  = (unsigned short*)carve(128 * 384 * 2);
  unsigned short* AG     = (unsigned short*)carve((size_t)n * 512 * 2);
  float*          Pqs    = (float*)carve((size_t)n * 128 * 4);
  float*          Psk    = (float*)carve((size_t)n * 128 * 4);
  float*          aS     = (float*)carve((size_t)n * HEADS * 4);
  float*          aD     = (float*)carve((size_t)n * HEADS * 4);
  unsigned short* FUS    = (unsigned short*)carve((size_t)n * 384 * 2);
  unsigned short* nbrb   = (unsigned short*)carve((size_t)n * 128 * 2);
  int* ideg   = (int*)carve((size_t)n * 4);
  int* offs   = (int*)carve(((size_t)n + 1) * 4);
  int* cursor = (int*)carve((size_t)n * 4);
  int* csrc   = (int*)carve((size_t)E * 4);
  const int NB = (n + 1023) / 1024;
  int* bsum   = (int*)carve((size_t)NB * 4);
  int* bpref  = (int*)carve((size_t)NB * 4);

  hipMemsetAsync(ideg, 0, n * sizeof(int), stream);

  prep_w<<<(164480 + 255) / 256, 256, 0, stream>>>(
      gat_w, wq, wk, wv, wsk, bq, bk, bv, bsk, swl, swr, fus_w,
      Wcat_t, Bcat, sage_t, fus_t);
  convert_x<<<(n * 32 + 255) / 256, 256, 0, stream>>>(x, AG, n);

  const int RB = (n + 127) / 128;  // 391

  // proj: [h q k v skip] = x @ Wcat + Bcat; y tile routes; y=0 also aS/aD
  gemm128<0><<<dim3(RB, 5), 256, 0, stream>>>(
      (const __hip_bfloat16*)(AG + 384), 512, nullptr, 0,
      (const __hip_bfloat16*)Wcat_t, 128, Bcat,
      AG, Pqs, Psk, aS, aD, att_s, att_d, nullptr, nullptr, nullptr, nullptr, n);

  deg_hist<<<(E + 255) / 256, 256, 0, stream>>>(ei, ideg, E);
  bsum_k<<<NB, 256, 0, stream>>>(ideg, bsum, n);
  bscan_k<<<1, 64, 0, stream>>>(bsum, bpref, offs + n, NB);
  offs_k<<<NB, 256, 0, stream>>>(ideg, bpref, offs, cursor, n);
  scatter_k<<<(E + 255) / 256, 256, 0, stream>>>(ei, cursor, csrc, E);

  aggregate<<<(n + 3) / 4, 256, 0, stream>>>(AG, Pqs, Psk, aS, aD, offs, csrc,
                                             gat_b, FUS, nbrb, n);

  // sage: [nbr | x] @ [swl; swr] + sbl, L2-normalized -> FUS[:,128:256)
  gemm128<1><<<dim3(RB, 1), 256, 0, stream>>>(
      (const __hip_bfloat16*)nbrb, 128, (const __hip_bfloat16*)(AG + 384), 512,
      (const __hip_bfloat16*)sage_t, 256, sbl,
      nullptr, nullptr, nullptr, nullptr, nullptr, nullptr, nullptr,
      FUS, nullptr, nullptr, nullptr, n);

  // out = FUS @ fus_w + fus_b, LayerNorm fused
  gemm128<2><<<dim3(RB, 1), 256, 0, stream>>>(
      (const __hip_bfloat16*)FUS, 384, nullptr, 0,
      (const __hip_bfloat16*)fus_t, 384, fus_b,
      nullptr, nullptr, nullptr, nullptr, nullptr, nullptr, nullptr,
      nullptr, out, ln_g, ln_b, n);
}

// Round 6
// 419.225 us; speedup vs baseline: 2.3485x; 1.0070x over previous
//
#include <hip/hip_runtime.h>
#include <hip/hip_bf16.h>
#include <math.h>

#define DIM 128
#define HEADS 8

typedef short short8 __attribute__((ext_vector_type(8)));
typedef float f32x4 __attribute__((ext_vector_type(4)));

#define GLD_LDS16(g, l) \
  __builtin_amdgcn_global_load_lds((const __attribute__((address_space(1))) void*)(g), \
                                   (__attribute__((address_space(3))) void*)(l), 16, 0, 0)

__device__ __forceinline__ float bf2f(unsigned short u) {
  union { unsigned int i; float f; } c; c.i = ((unsigned int)u) << 16; return c.f;
}
__device__ __forceinline__ unsigned short f2bf(float f) {
  __hip_bfloat16 h = __float2bfloat16(f);
  union { __hip_bfloat16 h; unsigned short u; } c; c.h = h; return c.u;
}
__device__ __forceinline__ float u_lo(unsigned int u) {
  union { unsigned int i; float f; } c; c.i = u << 16; return c.f;
}
__device__ __forceinline__ float u_hi(unsigned int u) {
  union { unsigned int i; float f; } c; c.i = u & 0xffff0000u; return c.f;
}

// ---------------- prep: transposed bf16 weights + Bcat --------------
// Wcat_t[768][128]: cols 0-127 h, 128-255 q, 256-383 k, 384-511 v,
// 512-639 skip, 640-647 Ws (a_src map), 648-655 Wd (a_dst map), 656-767 zero
__global__ void prep_w(const float* __restrict__ gw, const float* __restrict__ wq,
                       const float* __restrict__ wk, const float* __restrict__ wv,
                       const float* __restrict__ wsk,
                       const float* __restrict__ bq, const float* __restrict__ bk,
                       const float* __restrict__ bv, const float* __restrict__ bsk,
                       const float* __restrict__ atts, const float* __restrict__ attd,
                       const float* __restrict__ swl, const float* __restrict__ swr,
                       const float* __restrict__ fw,
                       unsigned short* __restrict__ Wcat_t, float* __restrict__ Bcat,
                       unsigned short* __restrict__ sage_t, unsigned short* __restrict__ fus_t) {
  int i = blockIdx.x * 256 + threadIdx.x;
  if (i < 98304) {                      // Wcat_t[768][128]
    int c = i >> 7, k = i & 127;
    int s = c >> 7, j = c & 127;
    float val;
    if (s <= 4) {
      const float* w = (s == 0) ? gw : (s == 1) ? wq : (s == 2) ? wk : (s == 3) ? wv : wsk;
      val = w[k * 128 + j];
    } else {
      if (j < 8) {
        float acc = 0.f;
#pragma unroll
        for (int t = 0; t < 16; ++t) acc += gw[k * 128 + j * 16 + t] * atts[j * 16 + t];
        val = acc;
      } else if (j < 16) {
        int h = j - 8;
        float acc = 0.f;
#pragma unroll
        for (int t = 0; t < 16; ++t) acc += gw[k * 128 + h * 16 + t] * attd[h * 16 + t];
        val = acc;
      } else {
        val = 0.f;
      }
    }
    Wcat_t[i] = f2bf(val);
  } else if (i < 131072) {              // sage_t[128][256]
    int t = i - 98304;
    int j = t >> 8, k = t & 255;
    float v = (k < 128) ? swl[k * 128 + j] : swr[(k - 128) * 128 + j];
    sage_t[t] = f2bf(v);
  } else if (i < 180224) {              // fus_t[128][384]
    int t = i - 131072;
    int j = t / 384, k = t - j * 384;
    fus_t[t] = f2bf(fw[k * 128 + j]);
  } else if (i < 180992) {              // Bcat[768]
    int c = i - 180224;
    int s = c >> 7, j = c & 127;
    Bcat[c] = (s == 1) ? bq[j] : (s == 2) ? bk[j] : (s == 3) ? bv[j] : (s == 4) ? bsk[j] : 0.f;
  }
}

// ---------------- x -> AG x-slab (bf16) -----------------------------
__global__ void convert_x(const float* __restrict__ x, unsigned short* __restrict__ AG, int n) {
  int i = blockIdx.x * 256 + threadIdx.x;
  if (i >= n * 32) return;
  int idx = i * 4;
  float4 v = *(const float4*)(x + idx);
  ushort4 u;
  u.x = f2bf(v.x); u.y = f2bf(v.y); u.z = f2bf(v.z); u.w = f2bf(v.w);
  *(ushort4*)(AG + (size_t)(idx >> 7) * 512 + 384 + (idx & 127)) = u;
}

// ---------------- bf16 MFMA GEMM, tile 128x128, fused epilogues ------
// EPI 0: proj (grid.y: 0=h, 1=q, 2=k, 3=v, 4=skip, 5=aS/aD)
// EPI 1: sage (+bias, L2-normalize row, write bf16 to FUS[:,128:256))
// EPI 2: fusion (+bias, LayerNorm row, write f32 out)
template <int EPI>
__global__ __launch_bounds__(256) void gemm128(
    const __hip_bfloat16* __restrict__ A0, int lda0,
    const __hip_bfloat16* __restrict__ A1, int lda1,
    const __hip_bfloat16* __restrict__ Bt, int K,
    const float* __restrict__ bias,
    unsigned short* __restrict__ AGo, float* __restrict__ Pq, float* __restrict__ Psk,
    float* __restrict__ aSo, float* __restrict__ aDo,
    unsigned short* __restrict__ FUSo, float* __restrict__ outF,
    const float* __restrict__ lng, const float* __restrict__ lnb,
    int M) {
  __shared__ char Asb[128 * 64];   // 128 rows x 32 bf16
  __shared__ char Bsb[128 * 64];   // 128 cols x 32 bf16
  int tid = threadIdx.x;
  int l = tid & 63, w = tid >> 6;
  int row0 = blockIdx.x * 128, col0 = blockIdx.y * 128;
  f32x4 acc[2][8] = {};

  for (int kt = 0; kt < K; kt += 32) {
    const __hip_bfloat16* Ap;
    int lda, kof;
    if (A1 != nullptr && kt >= 128) { Ap = A1; lda = lda1; kof = kt - 128; }
    else { Ap = A0; lda = lda0; kof = kt; }
#pragma unroll
    for (int it = 0; it < 2; ++it) {   // A: 512 chunks
      int c = it * 256 + tid;
      int r = c >> 2, cp = c & 3;
      int gp = cp ^ (r & 3);
      int gr = row0 + r; if (gr >= M) gr = M - 1;
      GLD_LDS16((const char*)(Ap + (size_t)gr * lda + kof) + gp * 16, Asb + c * 16);
    }
#pragma unroll
    for (int it = 0; it < 2; ++it) {   // B: 512 chunks
      int c = it * 256 + tid;
      int r = c >> 2, cp = c & 3;
      int gp = cp ^ (r & 3);
      GLD_LDS16((const char*)(Bt + (size_t)(col0 + r) * K + kt) + gp * 16, Bsb + c * 16);
    }
    __syncthreads();
    int g = l >> 4, ri = l & 15;
    short8 af[2], bfr[8];
#pragma unroll
    for (int m = 0; m < 2; ++m) {
      int r = w * 32 + m * 16 + ri;
      af[m] = *(const short8*)(Asb + r * 64 + ((g ^ (r & 3)) * 16));
    }
#pragma unroll
    for (int c4 = 0; c4 < 8; ++c4) {
      int r = c4 * 16 + ri;
      bfr[c4] = *(const short8*)(Bsb + r * 64 + ((g ^ (r & 3)) * 16));
    }
#pragma unroll
    for (int m = 0; m < 2; ++m)
#pragma unroll
      for (int c4 = 0; c4 < 8; ++c4)
        acc[m][c4] = __builtin_amdgcn_mfma_f32_16x16x32_bf16(af[m], bfr[c4], acc[m][c4], 0, 0, 0);
    __syncthreads();
  }

  int g = l >> 4, ri = l & 15;
  float bias_r[8];
#pragma unroll
  for (int c4 = 0; c4 < 8; ++c4) bias_r[c4] = bias[col0 + c4 * 16 + ri];

  if (EPI == 0) {
    int y = col0 >> 7;  // 0..5
    if (y == 5) {
      // only c4==0 columns (640..655) carry data: ri<8 -> aS, ri<16 -> aD
#pragma unroll
      for (int m = 0; m < 2; ++m) {
#pragma unroll
        for (int j = 0; j < 4; ++j) {
          int row = row0 + w * 32 + m * 16 + g * 4 + j;
          if (row >= M) continue;
          float v = acc[m][0][j];
          if (ri < 8) aSo[row * HEADS + ri] = v;
          else        aDo[row * HEADS + (ri - 8)] = v;
        }
      }
    } else {
#pragma unroll
      for (int m = 0; m < 2; ++m) {
#pragma unroll
        for (int j = 0; j < 4; ++j) {
          int row = row0 + w * 32 + m * 16 + g * 4 + j;
          if (row >= M) continue;
#pragma unroll
          for (int c4 = 0; c4 < 8; ++c4) {
            int c = c4 * 16 + ri;
            float v = acc[m][c4][j] + bias_r[c4];
            if (y == 0)      AGo[(size_t)row * 512 + c] = f2bf(v);
            else if (y == 1) Pq[(size_t)row * 128 + c] = v;
            else if (y == 2) AGo[(size_t)row * 512 + 128 + c] = f2bf(v);
            else if (y == 3) AGo[(size_t)row * 512 + 256 + c] = f2bf(v);
            else             Psk[(size_t)row * 128 + c] = v;
          }
        }
      }
    }
  } else {
    // full 128-col row lives in this block: per-(m,j) row reduce over c4 + 16 lanes
#pragma unroll
    for (int m = 0; m < 2; ++m) {
#pragma unroll
      for (int j = 0; j < 4; ++j) {
        int row = row0 + w * 32 + m * 16 + g * 4 + j;
        bool ok = (row < M);
        float v[8];
        float s = 0.f;
#pragma unroll
        for (int c4 = 0; c4 < 8; ++c4) {
          v[c4] = acc[m][c4][j] + bias_r[c4];
          if (EPI == 1) s += v[c4] * v[c4];
          else          s += v[c4];
        }
        s += __shfl_xor(s, 1); s += __shfl_xor(s, 2);
        s += __shfl_xor(s, 4); s += __shfl_xor(s, 8);
        if (EPI == 1) {
          float inv = 1.f / fmaxf(sqrtf(s), 1e-12f);
          if (ok) {
#pragma unroll
            for (int c4 = 0; c4 < 8; ++c4)
              FUSo[(size_t)row * 384 + 128 + c4 * 16 + ri] = f2bf(v[c4] * inv);
          }
        } else {
          float mu = s * (1.f / 128.f);
          float ss = 0.f;
#pragma unroll
          for (int c4 = 0; c4 < 8; ++c4) { float d = v[c4] - mu; ss += d * d; }
          ss += __shfl_xor(ss, 1); ss += __shfl_xor(ss, 2);
          ss += __shfl_xor(ss, 4); ss += __shfl_xor(ss, 8);
          float rstd = 1.f / sqrtf(ss * (1.f / 128.f) + 1e-5f);
          if (ok) {
#pragma unroll
            for (int c4 = 0; c4 < 8; ++c4) {
              int c = c4 * 16 + ri;
              outF[(size_t)row * 128 + c] = (v[c4] - mu) * rstd * lng[c] + lnb[c];
            }
          }
        }
      }
    }
  }
}

// ---------------- CSR build (hierarchical scan) ---------------------
__global__ void deg_hist(const int* __restrict__ ei, int* __restrict__ deg, int E) {
  int e = blockIdx.x * 256 + threadIdx.x;
  if (e < E) atomicAdd(&deg[ei[E + e]], 1);
}

__global__ void bsum_k(const int* __restrict__ deg, int* __restrict__ bsum, int n) {
  int blk = blockIdx.x, t = threadIdx.x;
  int base = blk * 1024 + t * 4;
  int s = 0;
  if (base + 3 < n) {
    int4 d = *(const int4*)(deg + base);
    s = d.x + d.y + d.z + d.w;
  } else {
#pragma unroll
    for (int j = 0; j < 4; ++j) { int i = base + j; if (i < n) s += deg[i]; }
  }
  int lane = t & 63, wid = t >> 6;
  int x = s;
#pragma unroll
  for (int d = 1; d < 64; d <<= 1) { int y = __shfl_up(x, d); if (lane >= d) x += y; }
  __shared__ int wsum[4];
  if (lane == 63) wsum[wid] = x;
  __syncthreads();
  if (t == 0) bsum[blk] = wsum[0] + wsum[1] + wsum[2] + wsum[3];
}

__global__ void bscan_k(const int* __restrict__ bsum, int* __restrict__ bpref,
                        int* __restrict__ total_out, int nb) {
  int lane = threadIdx.x;
  int carry = 0;
  for (int base = 0; base < nb; base += 64) {
    int i = base + lane;
    int v = (i < nb) ? bsum[i] : 0;
    int x = v;
#pragma unroll
    for (int d = 1; d < 64; d <<= 1) { int y = __shfl_up(x, d); if (lane >= d) x += y; }
    if (i < nb) bpref[i] = carry + x - v;
    carry += __shfl(x, 63);
  }
  if (lane == 0) total_out[0] = carry;
}

__global__ void offs_k(const int* __restrict__ deg, const int* __restrict__ bpref,
                       int* __restrict__ offs, int* __restrict__ cursor, int n) {
  int blk = blockIdx.x, t = threadIdx.x;
  int base = blk * 1024 + t * 4;
  int d0 = 0, d1 = 0, d2 = 0, d3 = 0;
  if (base + 3 < n) {
    int4 d = *(const int4*)(deg + base);
    d0 = d.x; d1 = d.y; d2 = d.z; d3 = d.w;
  } else {
    if (base + 0 < n) d0 = deg[base + 0];
    if (base + 1 < n) d1 = deg[base + 1];
    if (base + 2 < n) d2 = deg[base + 2];
    if (base + 3 < n) d3 = deg[base + 3];
  }
  int s = d0 + d1 + d2 + d3;
  int lane = t & 63, wid = t >> 6;
  int x = s;
#pragma unroll
  for (int d = 1; d < 64; d <<= 1) { int y = __shfl_up(x, d); if (lane >= d) x += y; }
  __shared__ int wsum[4];
  if (lane == 63) wsum[wid] = x;
  __syncthreads();
  int woff = 0;
  for (int ww = 0; ww < wid; ++ww) woff += wsum[ww];
  int excl = bpref[blk] + woff + x - s;
  int p0 = excl, p1 = excl + d0, p2 = p1 + d1, p3 = p2 + d2;
  if (base + 0 < n) { offs[base + 0] = p0; cursor[base + 0] = p0; }
  if (base + 1 < n) { offs[base + 1] = p1; cursor[base + 1] = p1; }
  if (base + 2 < n) { offs[base + 2] = p2; cursor[base + 2] = p2; }
  if (base + 3 < n) { offs[base + 3] = p3; cursor[base + 3] = p3; }
}

__global__ void scatter_k(const int* __restrict__ ei, int* __restrict__ cursor,
                          int* __restrict__ csrc, int E) {
  int e = blockIdx.x * 256 + threadIdx.x;
  if (e >= E) return;
  int src = ei[e], dst = ei[E + e];
  int pos = atomicAdd(&cursor[dst], 1);
  csrc[pos] = src;
}

// ---------------- per-node aggregation ------------------------------
// unnormalized softmax (inputs bounded: logits << 88, fp32 exp safe),
// 8-edge batched gathers, single base address + imm-offset loads
__global__ __launch_bounds__(256) void aggregate(
    const unsigned short* __restrict__ AG, const float* __restrict__ Pq,
    const float* __restrict__ Psk,
    const float* __restrict__ aS, const float* __restrict__ aD,
    const int* __restrict__ offs, const int* __restrict__ csrc,
    const float* __restrict__ gat_b,
    unsigned short* __restrict__ FUS, unsigned short* __restrict__ nbrb, int n) {
  int node = blockIdx.x * 4 + (threadIdx.x >> 6);
  if (node >= n) return;
  int lane = threadIdx.x & 63;
  int head = lane >> 3;
  float2 qv = *(const float2*)(Pq + (size_t)node * 128 + 2 * lane);
  float adst = aD[node * HEADS + head];

  // GAT self-loop init (no max subtraction: logits bounded, exp safe)
  float lg0 = aS[node * HEADS + head] + adst;
  lg0 = fmaxf(lg0, 0.2f * lg0);
  float w0 = __expf(lg0);
  const char* Anb = (const char*)AG + ((size_t)node << 10) + lane * 4;
  unsigned int hu0 = *(const unsigned int*)(Anb);
  float2 acc_g = { w0 * u_lo(hu0), w0 * u_hi(hu0) };
  float l_g = w0;

  float l_t = 0.f;
  float2 acc_t = {0.f, 0.f};
  float2 acc_s = {0.f, 0.f};

  int e0 = offs[node], e1 = offs[node + 1];

#define EDGE_UPDATE(HU, KU, VU, XU, AV)                                  \
  {                                                                      \
    float lg = (AV) + adst;                                              \
    lg = fmaxf(lg, 0.2f * lg);                                           \
    float wg = __expf(lg);                                               \
    acc_g.x += wg * u_lo(HU);                                            \
    acc_g.y += wg * u_hi(HU);                                            \
    l_g += wg;                                                           \
    float part = qv.x * u_lo(KU) + qv.y * u_hi(KU);                      \
    part += __shfl_xor(part, 1);                                         \
    part += __shfl_xor(part, 2);                                         \
    part += __shfl_xor(part, 4);                                         \
    float wt = __expf(part * 0.25f);                                     \
    acc_t.x += wt * u_lo(VU);                                            \
    acc_t.y += wt * u_hi(VU);                                            \
    l_t += wt;                                                           \
    acc_s.x += u_lo(XU);                                                 \
    acc_s.y += u_hi(XU);                                                 \
  }

#define LOAD_EDGE(u, si_a, hu_a, ku_a, vu_a, xu_a, av_a)                 \
  {                                                                      \
    const char* As = (const char*)AG + ((size_t)si_a[u] << 10) + lane * 4; \
    hu_a[u] = *(const unsigned int*)(As);                                \
    ku_a[u] = *(const unsigned int*)(As + 256);                          \
    vu_a[u] = *(const unsigned int*)(As + 512);                          \
    xu_a[u] = *(const unsigned int*)(As + 768);                          \
    av_a[u] = aS[si_a[u] * HEADS + head];                                \
  }

  int e = e0;
  for (; e + 8 <= e1; e += 8) {
    int si[8];
#pragma unroll
    for (int u = 0; u < 8; ++u) si[u] = csrc[e + u];
    unsigned int hu[8], ku[8], vu[8], xu[8];
    float av[8];
#pragma unroll
    for (int u = 0; u < 8; ++u) LOAD_EDGE(u, si, hu, ku, vu, xu, av);
#pragma unroll
    for (int u = 0; u < 8; ++u) EDGE_UPDATE(hu[u], ku[u], vu[u], xu[u], av[u]);
  }
  if (e + 4 <= e1) {
    int si[4];
#pragma unroll
    for (int u = 0; u < 4; ++u) si[u] = csrc[e + u];
    unsigned int hu[4], ku[4], vu[4], xu[4];
    float av[4];
#pragma unroll
    for (int u = 0; u < 4; ++u) LOAD_EDGE(u, si, hu, ku, vu, xu, av);
#pragma unroll
    for (int u = 0; u < 4; ++u) EDGE_UPDATE(hu[u], ku[u], vu[u], xu[u], av[u]);
    e += 4;
  }
  for (; e < e1; ++e) {
    int s = csrc[e];
    const char* As = (const char*)AG + ((size_t)s << 10) + lane * 4;
    unsigned int hu = *(const unsigned int*)(As);
    unsigned int ku = *(const unsigned int*)(As + 256);
    unsigned int vu = *(const unsigned int*)(As + 512);
    unsigned int xu = *(const unsigned int*)(As + 768);
    float av = aS[s * HEADS + head];
    EDGE_UPDATE(hu, ku, vu, xu, av);
  }
#undef EDGE_UPDATE
#undef LOAD_EDGE

  float gx = acc_g.x / l_g + gat_b[2 * lane];
  float gy = acc_g.y / l_g + gat_b[2 * lane + 1];
  ushort2 go = { f2bf(gx), f2bf(gy) };
  *(ushort2*)(FUS + (size_t)node * 384 + 2 * lane) = go;

  float2 skip = *(const float2*)(Psk + (size_t)node * 128 + 2 * lane);
  float tx, ty;
  if (l_t > 0.f) {
    tx = acc_t.x / l_t + skip.x;
    ty = acc_t.y / l_t + skip.y;
  } else { tx = skip.x; ty = skip.y; }
  ushort2 to = { f2bf(tx), f2bf(ty) };
  *(ushort2*)(FUS + (size_t)node * 384 + 256 + 2 * lane) = to;

  float dg = fmaxf((float)(e1 - e0), 1.f);
  float inv = 1.f / dg;
  ushort2 nb = { f2bf(acc_s.x * inv), f2bf(acc_s.y * inv) };
  *(ushort2*)(nbrb + (size_t)node * 128 + 2 * lane) = nb;
}

extern "C" void kernel_launch(void* const* d_in, const int* in_sizes, int n_in,
                              void* d_out, int out_size, void* d_ws, size_t ws_size,
                              hipStream_t stream) {
  const float* x      = (const float*)d_in[0];
  const int*   ei     = (const int*)d_in[1];
  const float* gat_w  = (const float*)d_in[2];
  const float* att_s  = (const float*)d_in[3];
  const float* att_d  = (const float*)d_in[4];
  const float* gat_b  = (const float*)d_in[5];
  const float* swl    = (const float*)d_in[6];
  const float* sbl    = (const float*)d_in[7];
  const float* swr    = (const float*)d_in[8];
  const float* wq     = (const float*)d_in[9];
  const float* bq     = (const float*)d_in[10];
  const float* wk     = (const float*)d_in[11];
  const float* bk     = (const float*)d_in[12];
  const float* wv     = (const float*)d_in[13];
  const float* bv     = (const float*)d_in[14];
  const float* wsk    = (const float*)d_in[15];
  const float* bsk    = (const float*)d_in[16];
  const float* fus_w  = (const float*)d_in[17];
  const float* fus_b  = (const float*)d_in[18];
  const float* ln_g   = (const float*)d_in[19];
  const float* ln_b   = (const float*)d_in[20];
  float* out = (float*)d_out;

  const int n = in_sizes[0] / DIM;  // 50000
  const int E = in_sizes[1] / 2;    // 800000

  char* wsb = (char*)d_ws;
  size_t o = 0;
  auto carve = [&](size_t bytes) { char* p = wsb + o; o += (bytes + 255) & ~(size_t)255; return p; };
  unsigned short* Wcat_t = (unsigned short*)carve(768 * 128 * 2);
  float*          Bcat   = (float*)carve(768 * 4);
  unsigned short* sage_t = (unsigned short*)carve(128 * 256 * 2);
  unsigned short* fus_t  = (unsigned short*)carve(128 * 384 * 2);
  unsigned short* AG     = (unsigned short*)carve((size_t)n * 512 * 2);
  float*          Pqs    = (float*)carve((size_t)n * 128 * 4);
  float*          Psk    = (float*)carve((size_t)n * 128 * 4);
  float*          aS     = (float*)carve((size_t)n * HEADS * 4);
  float*          aD     = (float*)carve((size_t)n * HEADS * 4);
  unsigned short* FUS    = (unsigned short*)carve((size_t)n * 384 * 2);
  unsigned short* nbrb   = (unsigned short*)carve((size_t)n * 128 * 2);
  int* ideg   = (int*)carve((size_t)n * 4);
  int* offs   = (int*)carve(((size_t)n + 1) * 4);
  int* cursor = (int*)carve((size_t)n * 4);
  int* csrc   = (int*)carve((size_t)E * 4);
  const int NB = (n + 1023) / 1024;
  int* bsum   = (int*)carve((size_t)NB * 4);
  int* bpref  = (int*)carve((size_t)NB * 4);

  hipMemsetAsync(ideg, 0, n * sizeof(int), stream);

  prep_w<<<(180992 + 255) / 256, 256, 0, stream>>>(
      gat_w, wq, wk, wv, wsk, bq, bk, bv, bsk, att_s, att_d, swl, swr, fus_w,
      Wcat_t, Bcat, sage_t, fus_t);
  convert_x<<<(n * 32 + 255) / 256, 256, 0, stream>>>(x, AG, n);

  const int RB = (n + 127) / 128;  // 391

  // proj: [h q k v skip aS aD] = x @ Wcat + Bcat; y tile routes
  gemm128<0><<<dim3(RB, 6), 256, 0, stream>>>(
      (const __hip_bfloat16*)(AG + 384), 512, nullptr, 0,
      (const __hip_bfloat16*)Wcat_t, 128, Bcat,
      AG, Pqs, Psk, aS, aD, nullptr, nullptr, nullptr, nullptr, n);

  deg_hist<<<(E + 255) / 256, 256, 0, stream>>>(ei, ideg, E);
  bsum_k<<<NB, 256, 0, stream>>>(ideg, bsum, n);
  bscan_k<<<1, 64, 0, stream>>>(bsum, bpref, offs + n, NB);
  offs_k<<<NB, 256, 0, stream>>>(ideg, bpref, offs, cursor, n);
  scatter_k<<<(E + 255) / 256, 256, 0, stream>>>(ei, cursor, csrc, E);

  aggregate<<<(n + 3) / 4, 256, 0, stream>>>(AG, Pqs, Psk, aS, aD, offs, csrc,
                                             gat_b, FUS, nbrb, n);

  // sage: [nbr | x] @ [swl; swr] + sbl, L2-normalized -> FUS[:,128:256)
  gemm128<1><<<dim3(RB, 1), 256, 0, stream>>>(
      (const __hip_bfloat16*)nbrb, 128, (const __hip_bfloat16*)(AG + 384), 512,
      (const __hip_bfloat16*)sage_t, 256, sbl,
      nullptr, nullptr, nullptr, nullptr, nullptr,
      FUS, nullptr, nullptr, nullptr, n);

  // out = FUS @ fus_w + fus_b, LayerNorm fused
  gemm128<2><<<dim3(RB, 1), 256, 0, stream>>>(
      (const __hip_bfloat16*)FUS, 384, nullptr, 0,
      (const __hip_bfloat16*)fus_t, 384, fus_b,
      nullptr, nullptr, nullptr, nullptr, nullptr,
      nullptr, out, ln_g, ln_b, n);
}

// Round 7
// 379.182 us; speedup vs baseline: 2.5965x; 1.1056x over previous
//
#include <hip/hip_runtime.h>
#include <hip/hip_bf16.h>
#include <hip/hip_fp16.h>
#include <hip/hip_fp8.h>
#include <math.h>

#define DIM 128
#define HEADS 8
#define ROWB 672   // AG row: [k:0 bf16x128 | h:256 fp8x128 | v:384 fp8x128 | x:512 e5m2x128 | aS:640 f32x8]

typedef short short8 __attribute__((ext_vector_type(8)));
typedef float f32x4 __attribute__((ext_vector_type(4)));

#define GLD_LDS16(g, l) \
  __builtin_amdgcn_global_load_lds((const __attribute__((address_space(1))) void*)(g), \
                                   (__attribute__((address_space(3))) void*)(l), 16, 0, 0)

__device__ __forceinline__ float bf2f(unsigned short u) {
  union { unsigned int i; float f; } c; c.i = ((unsigned int)u) << 16; return c.f;
}
__device__ __forceinline__ unsigned short f2bf(float f) {
  __hip_bfloat16 h = __float2bfloat16(f);
  union { __hip_bfloat16 h; unsigned short u; } c; c.h = h; return c.u;
}
__device__ __forceinline__ float u_lo(unsigned int u) {
  union { unsigned int i; float f; } c; c.i = u << 16; return c.f;
}
__device__ __forceinline__ float u_hi(unsigned int u) {
  union { unsigned int i; float f; } c; c.i = u & 0xffff0000u; return c.f;
}
__device__ __forceinline__ unsigned char f_fp8(float f) {
  __hip_fp8_e4m3 t(f);
  return (unsigned char)t.__x;
}
__device__ __forceinline__ float fp8_f(unsigned char b) {
  __hip_fp8_e4m3 t; t.__x = (__hip_fp8_storage_t)b; return (float)t;
}
__device__ __forceinline__ unsigned char f_e5m2(float f) {
  unsigned short u = __half_as_ushort(__float2half(f));
  unsigned short r = (unsigned short)((u + 0x7F + ((u >> 8) & 1)) >> 8);
  return (unsigned char)r;
}
__device__ __forceinline__ float e5m2_f(unsigned char b) {
  return __half2float(__ushort_as_half((unsigned short)(((unsigned short)b) << 8)));
}

// ---------------- prep: transposed bf16 weights + Bcat --------------
// Wcat_t[768][128]: 0-127 h, 128-255 q, 256-383 k, 384-511 v,
// 512-639 skip, 640-647 Ws(a_src), 648-655 Wd(a_dst), 656-767 zero
__global__ void prep_w(const float* __restrict__ gw, const float* __restrict__ wq,
                       const float* __restrict__ wk, const float* __restrict__ wv,
                       const float* __restrict__ wsk,
                       const float* __restrict__ bq, const float* __restrict__ bk,
                       const float* __restrict__ bv, const float* __restrict__ bsk,
                       const float* __restrict__ atts, const float* __restrict__ attd,
                       const float* __restrict__ swl, const float* __restrict__ swr,
                       const float* __restrict__ fw,
                       unsigned short* __restrict__ Wcat_t, float* __restrict__ Bcat,
                       unsigned short* __restrict__ sage_t, unsigned short* __restrict__ fus_t) {
  int i = blockIdx.x * 256 + threadIdx.x;
  if (i < 98304) {                      // Wcat_t[768][128]
    int c = i >> 7, k = i & 127;
    int s = c >> 7, j = c & 127;
    float val;
    if (s <= 4) {
      const float* w = (s == 0) ? gw : (s == 1) ? wq : (s == 2) ? wk : (s == 3) ? wv : wsk;
      val = w[k * 128 + j];
    } else {
      if (j < 8) {
        float acc = 0.f;
#pragma unroll
        for (int t = 0; t < 16; ++t) acc += gw[k * 128 + j * 16 + t] * atts[j * 16 + t];
        val = acc;
      } else if (j < 16) {
        int h = j - 8;
        float acc = 0.f;
#pragma unroll
        for (int t = 0; t < 16; ++t) acc += gw[k * 128 + h * 16 + t] * attd[h * 16 + t];
        val = acc;
      } else {
        val = 0.f;
      }
    }
    Wcat_t[i] = f2bf(val);
  } else if (i < 131072) {              // sage_t[128][256]
    int t = i - 98304;
    int j = t >> 8, k = t & 255;
    float v = (k < 128) ? swl[k * 128 + j] : swr[(k - 128) * 128 + j];
    sage_t[t] = f2bf(v);
  } else if (i < 180224) {              // fus_t[128][384]
    int t = i - 131072;
    int j = t / 384, k = t - j * 384;
    fus_t[t] = f2bf(fw[k * 128 + j]);
  } else if (i < 180992) {              // Bcat[768]
    int c = i - 180224;
    int s = c >> 7, j = c & 127;
    Bcat[c] = (s == 1) ? bq[j] : (s == 2) ? bk[j] : (s == 3) ? bv[j] : (s == 4) ? bsk[j] : 0.f;
  }
}

// ---------------- x -> Xb (bf16 GEMM copy) + AG x-slab (e5m2) + deg hist
__global__ void conv_hist(const float* __restrict__ x, unsigned short* __restrict__ Xb,
                          unsigned char* __restrict__ AG,
                          const int* __restrict__ ei, int* __restrict__ ideg,
                          int n, int E, int CB) {
  int b = blockIdx.x;
  if (b < CB) {
    int i = b * 256 + threadIdx.x;
    if (i >= n * 32) return;
    int node = i >> 5, c = (i & 31) * 4;
    float4 v = *(const float4*)(x + (size_t)node * 128 + c);
    ushort4 ub = { f2bf(v.x), f2bf(v.y), f2bf(v.z), f2bf(v.w) };
    *(ushort4*)(Xb + (size_t)node * 128 + c) = ub;
    uchar4 u8 = { f_e5m2(v.x), f_e5m2(v.y), f_e5m2(v.z), f_e5m2(v.w) };
    *(uchar4*)(AG + (size_t)node * ROWB + 512 + c) = u8;
  } else {
    int t = (b - CB) * 256 + threadIdx.x;
    int stride = (gridDim.x - CB) * 256;
    for (int e = t; e < E; e += stride) atomicAdd(&ideg[ei[E + e]], 1);
  }
}

// ---------------- bf16 MFMA GEMM, tile 128x128, fused epilogues ------
// EPI 0: proj (grid.y: 0=h(fp8), 1=q(f32), 2=k(bf16), 3=v(fp8), 4=skip(f32), 5=aS(AG)/aD)
// EPI 1: sage (+bias, L2-normalize row, bf16 -> FUS[:,128:256))
// EPI 2: fusion (+bias, LayerNorm row, f32 out)
template <int EPI>
__global__ __launch_bounds__(256) void gemm128(
    const __hip_bfloat16* __restrict__ A0, int lda0,
    const __hip_bfloat16* __restrict__ A1, int lda1,
    const __hip_bfloat16* __restrict__ Bt, int K,
    const float* __restrict__ bias,
    unsigned char* __restrict__ AGo, float* __restrict__ Pq, float* __restrict__ Psk,
    float* __restrict__ aDo,
    unsigned short* __restrict__ FUSo, float* __restrict__ outF,
    const float* __restrict__ lng, const float* __restrict__ lnb,
    int M) {
  __shared__ char Asb[128 * 64];
  __shared__ char Bsb[128 * 64];
  int tid = threadIdx.x;
  int l = tid & 63, w = tid >> 6;
  int row0 = blockIdx.x * 128, col0 = blockIdx.y * 128;
  f32x4 acc[2][8] = {};

  for (int kt = 0; kt < K; kt += 32) {
    const __hip_bfloat16* Ap;
    int lda, kof;
    if (A1 != nullptr && kt >= 128) { Ap = A1; lda = lda1; kof = kt - 128; }
    else { Ap = A0; lda = lda0; kof = kt; }
#pragma unroll
    for (int it = 0; it < 2; ++it) {
      int c = it * 256 + tid;
      int r = c >> 2, cp = c & 3;
      int gp = cp ^ (r & 3);
      int gr = row0 + r; if (gr >= M) gr = M - 1;
      GLD_LDS16((const char*)(Ap + (size_t)gr * lda + kof) + gp * 16, Asb + c * 16);
    }
#pragma unroll
    for (int it = 0; it < 2; ++it) {
      int c = it * 256 + tid;
      int r = c >> 2, cp = c & 3;
      int gp = cp ^ (r & 3);
      GLD_LDS16((const char*)(Bt + (size_t)(col0 + r) * K + kt) + gp * 16, Bsb + c * 16);
    }
    __syncthreads();
    int g = l >> 4, ri = l & 15;
    short8 af[2], bfr[8];
#pragma unroll
    for (int m = 0; m < 2; ++m) {
      int r = w * 32 + m * 16 + ri;
      af[m] = *(const short8*)(Asb + r * 64 + ((g ^ (r & 3)) * 16));
    }
#pragma unroll
    for (int c4 = 0; c4 < 8; ++c4) {
      int r = c4 * 16 + ri;
      bfr[c4] = *(const short8*)(Bsb + r * 64 + ((g ^ (r & 3)) * 16));
    }
#pragma unroll
    for (int m = 0; m < 2; ++m)
#pragma unroll
      for (int c4 = 0; c4 < 8; ++c4)
        acc[m][c4] = __builtin_amdgcn_mfma_f32_16x16x32_bf16(af[m], bfr[c4], acc[m][c4], 0, 0, 0);
    __syncthreads();
  }

  int g = l >> 4, ri = l & 15;
  float bias_r[8];
#pragma unroll
  for (int c4 = 0; c4 < 8; ++c4) bias_r[c4] = bias[col0 + c4 * 16 + ri];

  if (EPI == 0) {
    int y = col0 >> 7;  // 0..5
    if (y == 5) {
#pragma unroll
      for (int m = 0; m < 2; ++m) {
#pragma unroll
        for (int j = 0; j < 4; ++j) {
          int row = row0 + w * 32 + m * 16 + g * 4 + j;
          if (row >= M) continue;
          float v = acc[m][0][j];
          if (ri < 8) *(float*)(AGo + (size_t)row * ROWB + 640 + ri * 4) = v;
          else        aDo[row * HEADS + (ri - 8)] = v;
        }
      }
    } else {
#pragma unroll
      for (int m = 0; m < 2; ++m) {
#pragma unroll
        for (int j = 0; j < 4; ++j) {
          int row = row0 + w * 32 + m * 16 + g * 4 + j;
          if (row >= M) continue;
#pragma unroll
          for (int c4 = 0; c4 < 8; ++c4) {
            int c = c4 * 16 + ri;
            float v = acc[m][c4][j] + bias_r[c4];
            if (y == 0)      AGo[(size_t)row * ROWB + 256 + c] = f_fp8(v);
            else if (y == 1) Pq[(size_t)row * 128 + c] = v;
            else if (y == 2) *(unsigned short*)(AGo + (size_t)row * ROWB + c * 2) = f2bf(v);
            else if (y == 3) AGo[(size_t)row * ROWB + 384 + c] = f_fp8(v);
            else             Psk[(size_t)row * 128 + c] = v;
          }
        }
      }
    }
  } else {
#pragma unroll
    for (int m = 0; m < 2; ++m) {
#pragma unroll
      for (int j = 0; j < 4; ++j) {
        int row = row0 + w * 32 + m * 16 + g * 4 + j;
        bool ok = (row < M);
        float v[8];
        float s = 0.f;
#pragma unroll
        for (int c4 = 0; c4 < 8; ++c4) {
          v[c4] = acc[m][c4][j] + bias_r[c4];
          if (EPI == 1) s += v[c4] * v[c4];
          else          s += v[c4];
        }
        s += __shfl_xor(s, 1); s += __shfl_xor(s, 2);
        s += __shfl_xor(s, 4); s += __shfl_xor(s, 8);
        if (EPI == 1) {
          float inv = 1.f / fmaxf(sqrtf(s), 1e-12f);
          if (ok) {
#pragma unroll
            for (int c4 = 0; c4 < 8; ++c4)
              FUSo[(size_t)row * 384 + 128 + c4 * 16 + ri] = f2bf(v[c4] * inv);
          }
        } else {
          float mu = s * (1.f / 128.f);
          float ss = 0.f;
#pragma unroll
          for (int c4 = 0; c4 < 8; ++c4) { float d = v[c4] - mu; ss += d * d; }
          ss += __shfl_xor(ss, 1); ss += __shfl_xor(ss, 2);
          ss += __shfl_xor(ss, 4); ss += __shfl_xor(ss, 8);
          float rstd = 1.f / sqrtf(ss * (1.f / 128.f) + 1e-5f);
          if (ok) {
#pragma unroll
            for (int c4 = 0; c4 < 8; ++c4) {
              int c = c4 * 16 + ri;
              outF[(size_t)row * 128 + c] = (v[c4] - mu) * rstd * lng[c] + lnb[c];
            }
          }
        }
      }
    }
  }
}

// ---------------- CSR build (hierarchical scan) ---------------------
__global__ void bsum_k(const int* __restrict__ deg, int* __restrict__ bsum, int n) {
  int blk = blockIdx.x, t = threadIdx.x;
  int base = blk * 1024 + t * 4;
  int s = 0;
  if (base + 3 < n) {
    int4 d = *(const int4*)(deg + base);
    s = d.x + d.y + d.z + d.w;
  } else {
#pragma unroll
    for (int j = 0; j < 4; ++j) { int i = base + j; if (i < n) s += deg[i]; }
  }
  int lane = t & 63, wid = t >> 6;
  int x = s;
#pragma unroll
  for (int d = 1; d < 64; d <<= 1) { int y = __shfl_up(x, d); if (lane >= d) x += y; }
  __shared__ int wsum[4];
  if (lane == 63) wsum[wid] = x;
  __syncthreads();
  if (t == 0) bsum[blk] = wsum[0] + wsum[1] + wsum[2] + wsum[3];
}

__global__ void bscan_k(const int* __restrict__ bsum, int* __restrict__ bpref,
                        int* __restrict__ total_out, int nb) {
  int lane = threadIdx.x;
  int carry = 0;
  for (int base = 0; base < nb; base += 64) {
    int i = base + lane;
    int v = (i < nb) ? bsum[i] : 0;
    int x = v;
#pragma unroll
    for (int d = 1; d < 64; d <<= 1) { int y = __shfl_up(x, d); if (lane >= d) x += y; }
    if (i < nb) bpref[i] = carry + x - v;
    carry += __shfl(x, 63);
  }
  if (lane == 0) total_out[0] = carry;
}

__global__ void offs_k(const int* __restrict__ deg, const int* __restrict__ bpref,
                       int* __restrict__ offs, int* __restrict__ cursor, int n) {
  int blk = blockIdx.x, t = threadIdx.x;
  int base = blk * 1024 + t * 4;
  int d0 = 0, d1 = 0, d2 = 0, d3 = 0;
  if (base + 3 < n) {
    int4 d = *(const int4*)(deg + base);
    d0 = d.x; d1 = d.y; d2 = d.z; d3 = d.w;
  } else {
    if (base + 0 < n) d0 = deg[base + 0];
    if (base + 1 < n) d1 = deg[base + 1];
    if (base + 2 < n) d2 = deg[base + 2];
    if (base + 3 < n) d3 = deg[base + 3];
  }
  int s = d0 + d1 + d2 + d3;
  int lane = t & 63, wid = t >> 6;
  int x = s;
#pragma unroll
  for (int d = 1; d < 64; d <<= 1) { int y = __shfl_up(x, d); if (lane >= d) x += y; }
  __shared__ int wsum[4];
  if (lane == 63) wsum[wid] = x;
  __syncthreads();
  int woff = 0;
  for (int ww = 0; ww < wid; ++ww) woff += wsum[ww];
  int excl = bpref[blk] + woff + x - s;
  int p0 = excl, p1 = excl + d0, p2 = p1 + d1, p3 = p2 + d2;
  if (base + 0 < n) { offs[base + 0] = p0; cursor[base + 0] = p0; }
  if (base + 1 < n) { offs[base + 1] = p1; cursor[base + 1] = p1; }
  if (base + 2 < n) { offs[base + 2] = p2; cursor[base + 2] = p2; }
  if (base + 3 < n) { offs[base + 3] = p3; cursor[base + 3] = p3; }
}

__global__ void scatter_k(const int* __restrict__ ei, int* __restrict__ cursor,
                          int* __restrict__ csrc, int E) {
  int e = blockIdx.x * 256 + threadIdx.x;
  if (e >= E) return;
  int src = ei[e], dst = ei[E + e];
  int pos = atomicAdd(&cursor[dst], 1);
  csrc[pos] = src;
}

// ---------------- per-node aggregation ------------------------------
// unnormalized softmax; 8-edge batching; 672B row gathers with in-row aS
__global__ __launch_bounds__(256) void aggregate(
    const unsigned char* __restrict__ AG, const float* __restrict__ Pq,
    const float* __restrict__ Psk, const float* __restrict__ aD,
    const int* __restrict__ offs, const int* __restrict__ csrc,
    const float* __restrict__ gat_b,
    unsigned short* __restrict__ FUS, unsigned short* __restrict__ nbrb, int n) {
  int node = blockIdx.x * 4 + (threadIdx.x >> 6);
  if (node >= n) return;
  int lane = threadIdx.x & 63;
  int head = lane >> 3;
  float2 qv = *(const float2*)(Pq + (size_t)node * 128 + 2 * lane);
  float adst = aD[node * HEADS + head];

  const unsigned char* An = AG + (size_t)node * ROWB;
  float lg0 = *(const float*)(An + 640 + head * 4) + adst;
  lg0 = fmaxf(lg0, 0.2f * lg0);
  float w0 = __expf(lg0);
  unsigned short h0raw = *(const unsigned short*)(An + 256 + lane * 2);
  float2 acc_g = { w0 * fp8_f((unsigned char)(h0raw & 0xff)),
                   w0 * fp8_f((unsigned char)(h0raw >> 8)) };
  float l_g = w0;

  float l_t = 0.f;
  float2 acc_t = {0.f, 0.f};
  float2 acc_s = {0.f, 0.f};

  int e0 = offs[node], e1 = offs[node + 1];

#define EDGE_UPDATE(KU, HR, VR, XR, AV)                                  \
  {                                                                      \
    float lg = (AV) + adst;                                              \
    lg = fmaxf(lg, 0.2f * lg);                                           \
    float wg = __expf(lg);                                               \
    acc_g.x += wg * fp8_f((unsigned char)((HR) & 0xff));                 \
    acc_g.y += wg * fp8_f((unsigned char)((HR) >> 8));                   \
    l_g += wg;                                                           \
    float part = qv.x * u_lo(KU) + qv.y * u_hi(KU);                      \
    part += __shfl_xor(part, 1);                                         \
    part += __shfl_xor(part, 2);                                         \
    part += __shfl_xor(part, 4);                                         \
    float wt = __expf(part * 0.25f);                                     \
    acc_t.x += wt * fp8_f((unsigned char)((VR) & 0xff));                 \
    acc_t.y += wt * fp8_f((unsigned char)((VR) >> 8));                   \
    l_t += wt;                                                           \
    acc_s.x += e5m2_f((unsigned char)((XR) & 0xff));                     \
    acc_s.y += e5m2_f((unsigned char)((XR) >> 8));                       \
  }

#define LOAD_EDGE(u, si_a, ku_a, hr_a, vr_a, xr_a, av_a)                 \
  {                                                                      \
    const unsigned char* As = AG + (size_t)si_a[u] * ROWB;               \
    ku_a[u] = *(const unsigned int*)(As + lane * 4);                     \
    hr_a[u] = *(const unsigned short*)(As + 256 + lane * 2);             \
    vr_a[u] = *(const unsigned short*)(As + 384 + lane * 2);             \
    xr_a[u] = *(const unsigned short*)(As + 512 + lane * 2);             \
    av_a[u] = *(const float*)(As + 640 + head * 4);                      \
  }

  int e = e0;
  for (; e + 8 <= e1; e += 8) {
    int si[8];
#pragma unroll
    for (int u = 0; u < 8; ++u) si[u] = csrc[e + u];
    unsigned int ku[8];
    unsigned short hr[8], vr[8], xr[8];
    float av[8];
#pragma unroll
    for (int u = 0; u < 8; ++u) LOAD_EDGE(u, si, ku, hr, vr, xr, av);
#pragma unroll
    for (int u = 0; u < 8; ++u) EDGE_UPDATE(ku[u], hr[u], vr[u], xr[u], av[u]);
  }
  if (e + 4 <= e1) {
    int si[4];
#pragma unroll
    for (int u = 0; u < 4; ++u) si[u] = csrc[e + u];
    unsigned int ku[4];
    unsigned short hr[4], vr[4], xr[4];
    float av[4];
#pragma unroll
    for (int u = 0; u < 4; ++u) LOAD_EDGE(u, si, ku, hr, vr, xr, av);
#pragma unroll
    for (int u = 0; u < 4; ++u) EDGE_UPDATE(ku[u], hr[u], vr[u], xr[u], av[u]);
    e += 4;
  }
  for (; e < e1; ++e) {
    int s = csrc[e];
    const unsigned char* As = AG + (size_t)s * ROWB;
    unsigned int ku = *(const unsigned int*)(As + lane * 4);
    unsigned short hr = *(const unsigned short*)(As + 256 + lane * 2);
    unsigned short vr = *(const unsigned short*)(As + 384 + lane * 2);
    unsigned short xr = *(const unsigned short*)(As + 512 + lane * 2);
    float av = *(const float*)(As + 640 + head * 4);
    EDGE_UPDATE(ku, hr, vr, xr, av);
  }
#undef EDGE_UPDATE
#undef LOAD_EDGE

  float gx = acc_g.x / l_g + gat_b[2 * lane];
  float gy = acc_g.y / l_g + gat_b[2 * lane + 1];
  ushort2 go = { f2bf(gx), f2bf(gy) };
  *(ushort2*)(FUS + (size_t)node * 384 + 2 * lane) = go;

  float2 skip = *(const float2*)(Psk + (size_t)node * 128 + 2 * lane);
  float tx, ty;
  if (l_t > 0.f) {
    tx = acc_t.x / l_t + skip.x;
    ty = acc_t.y / l_t + skip.y;
  } else { tx = skip.x; ty = skip.y; }
  ushort2 to = { f2bf(tx), f2bf(ty) };
  *(ushort2*)(FUS + (size_t)node * 384 + 256 + 2 * lane) = to;

  float dg = fmaxf((float)(e1 - e0), 1.f);
  float inv = 1.f / dg;
  ushort2 nb = { f2bf(acc_s.x * inv), f2bf(acc_s.y * inv) };
  *(ushort2*)(nbrb + (size_t)node * 128 + 2 * lane) = nb;
}

extern "C" void kernel_launch(void* const* d_in, const int* in_sizes, int n_in,
                              void* d_out, int out_size, void* d_ws, size_t ws_size,
                              hipStream_t stream) {
  const float* x      = (const float*)d_in[0];
  const int*   ei     = (const int*)d_in[1];
  const float* gat_w  = (const float*)d_in[2];
  const float* att_s  = (const float*)d_in[3];
  const float* att_d  = (const float*)d_in[4];
  const float* gat_b  = (const float*)d_in[5];
  const float* swl    = (const float*)d_in[6];
  const float* sbl    = (const float*)d_in[7];
  const float* swr    = (const float*)d_in[8];
  const float* wq     = (const float*)d_in[9];
  const float* bq     = (const float*)d_in[10];
  const float* wk     = (const float*)d_in[11];
  const float* bk     = (const float*)d_in[12];
  const float* wv     = (const float*)d_in[13];
  const float* bv     = (const float*)d_in[14];
  const float* wsk    = (const float*)d_in[15];
  const float* bsk    = (const float*)d_in[16];
  const float* fus_w  = (const float*)d_in[17];
  const float* fus_b  = (const float*)d_in[18];
  const float* ln_g   = (const float*)d_in[19];
  const float* ln_b   = (const float*)d_in[20];
  float* out = (float*)d_out;

  const int n = in_sizes[0] / DIM;  // 50000
  const int E = in_sizes[1] / 2;    // 800000

  char* wsb = (char*)d_ws;
  size_t o = 0;
  auto carve = [&](size_t bytes) { char* p = wsb + o; o += (bytes + 255) & ~(size_t)255; return p; };
  unsigned short* Wcat_t = (unsigned short*)carve(768 * 128 * 2);
  float*          Bcat   = (float*)carve(768 * 4);
  unsigned short* sage_t = (unsigned short*)carve(128 * 256 * 2);
  unsigned short* fus_t  = (unsigned short*)carve(128 * 384 * 2);
  unsigned char*  AG     = (unsigned char*)carve((size_t)n * ROWB);
  unsigned short* Xb     = (unsigned short*)carve((size_t)n * 128 * 2);
  float*          Pqs    = (float*)carve((size_t)n * 128 * 4);
  float*          Psk    = (float*)carve((size_t)n * 128 * 4);
  float*          aDa    = (float*)carve((size_t)n * HEADS * 4);
  unsigned short* FUS    = (unsigned short*)carve((size_t)n * 384 * 2);
  unsigned short* nbrb   = (unsigned short*)carve((size_t)n * 128 * 2);
  int* ideg   = (int*)carve((size_t)n * 4);
  int* offs   = (int*)carve(((size_t)n + 1) * 4);
  int* cursor = (int*)carve((size_t)n * 4);
  int* csrc   = (int*)carve((size_t)E * 4);
  const int NB = (n + 1023) / 1024;
  int* bsum   = (int*)carve((size_t)NB * 4);
  int* bpref  = (int*)carve((size_t)NB * 4);

  hipMemsetAsync(ideg, 0, n * sizeof(int), stream);

  prep_w<<<(180992 + 255) / 256, 256, 0, stream>>>(
      gat_w, wq, wk, wv, wsk, bq, bk, bv, bsk, att_s, att_d, swl, swr, fus_w,
      Wcat_t, Bcat, sage_t, fus_t);

  const int CB = (n * 32 + 255) / 256;           // convert blocks
  const int HB = (E + 255) / 256 / 2;            // hist blocks (grid-stride x2)
  conv_hist<<<CB + HB, 256, 0, stream>>>(x, Xb, AG, ei, ideg, n, E, CB);

  const int RB = (n + 127) / 128;  // 391

  // proj: [h q k v skip aS aD] = x @ Wcat + Bcat; y tile routes
  gemm128<0><<<dim3(RB, 6), 256, 0, stream>>>(
      (const __hip_bfloat16*)Xb, 128, nullptr, 0,
      (const __hip_bfloat16*)Wcat_t, 128, Bcat,
      AG, Pqs, Psk, aDa, nullptr, nullptr, nullptr, nullptr, n);

  bsum_k<<<NB, 256, 0, stream>>>(ideg, bsum, n);
  bscan_k<<<1, 64, 0, stream>>>(bsum, bpref, offs + n, NB);
  offs_k<<<NB, 256, 0, stream>>>(ideg, bpref, offs, cursor, n);
  scatter_k<<<(E + 255) / 256, 256, 0, stream>>>(ei, cursor, csrc, E);

  aggregate<<<(n + 3) / 4, 256, 0, stream>>>(AG, Pqs, Psk, aDa, offs, csrc,
                                             gat_b, FUS, nbrb, n);

  // sage: [nbr | x] @ [swl; swr] + sbl, L2-normalized -> FUS[:,128:256)
  gemm128<1><<<dim3(RB, 1), 256, 0, stream>>>(
      (const __hip_bfloat16*)nbrb, 128, (const __hip_bfloat16*)Xb, 128,
      (const __hip_bfloat16*)sage_t, 256, sbl,
      nullptr, nullptr, nullptr, nullptr,
      FUS, nullptr, nullptr, nullptr, n);

  // out = FUS @ fus_w + fus_b, LayerNorm fused
  gemm128<2><<<dim3(RB, 1), 256, 0, stream>>>(
      (const __hip_bfloat16*)FUS, 384, nullptr, 0,
      (const __hip_bfloat16*)fus_t, 384, fus_b,
      nullptr, nullptr, nullptr, nullptr,
      nullptr, out, ln_g, ln_b, n);
}

// Round 9
// 371.688 us; speedup vs baseline: 2.6488x; 1.0202x over previous
//
#include <hip/hip_runtime.h>
#include <hip/hip_bf16.h>
#include <hip/hip_fp16.h>
#include <hip/hip_fp8.h>
#include <math.h>

#define DIM 128
#define HEADS 8
#define ROWB 768   // AG row, 128B-aligned segments:
                   // [k:0 bf16x128 | h:256 fp8x128 | v:384 fp8x128 | x:512 fp8x128 | aS:640 f32x8 | pad]

typedef short short8 __attribute__((ext_vector_type(8)));
typedef float f32x4 __attribute__((ext_vector_type(4)));

#define GLD_LDS16(g, l) \
  __builtin_amdgcn_global_load_lds((const __attribute__((address_space(1))) void*)(g), \
                                   (__attribute__((address_space(3))) void*)(l), 16, 0, 0)

__device__ __forceinline__ float bf2f(unsigned short u) {
  union { unsigned int i; float f; } c; c.i = ((unsigned int)u) << 16; return c.f;
}
__device__ __forceinline__ unsigned short f2bf(float f) {
  __hip_bfloat16 h = __float2bfloat16(f);
  union { __hip_bfloat16 h; unsigned short u; } c; c.h = h; return c.u;
}
__device__ __forceinline__ float u_lo(unsigned int u) {
  union { unsigned int i; float f; } c; c.i = u << 16; return c.f;
}
__device__ __forceinline__ float u_hi(unsigned int u) {
  union { unsigned int i; float f; } c; c.i = u & 0xffff0000u; return c.f;
}
__device__ __forceinline__ unsigned char f_fp8(float f) {
  __hip_fp8_e4m3 t(f);
  return (unsigned char)t.__x;
}
__device__ __forceinline__ float fp8_f(unsigned char b) {
  __hip_fp8_e4m3 t; t.__x = (__hip_fp8_storage_t)b; return (float)t;
}

// ---------------- prep: transposed bf16 weights + Bcat --------------
// Wcat_t[768][128]: 0-127 h, 128-255 q, 256-383 k, 384-511 v,
// 512-639 skip, 640-647 Ws(a_src), 648-655 Wd(a_dst), 656-767 zero
__global__ void prep_w(const float* __restrict__ gw, const float* __restrict__ wq,
                       const float* __restrict__ wk, const float* __restrict__ wv,
                       const float* __restrict__ wsk,
                       const float* __restrict__ bq, const float* __restrict__ bk,
                       const float* __restrict__ bv, const float* __restrict__ bsk,
                       const float* __restrict__ atts, const float* __restrict__ attd,
                       const float* __restrict__ swl, const float* __restrict__ swr,
                       const float* __restrict__ fw,
                       unsigned short* __restrict__ Wcat_t, float* __restrict__ Bcat,
                       unsigned short* __restrict__ sage_t, unsigned short* __restrict__ fus_t) {
  int i = blockIdx.x * 256 + threadIdx.x;
  if (i < 98304) {                      // Wcat_t[768][128]
    int c = i >> 7, k = i & 127;
    int s = c >> 7, j = c & 127;
    float val;
    if (s <= 4) {
      const float* w = (s == 0) ? gw : (s == 1) ? wq : (s == 2) ? wk : (s == 3) ? wv : wsk;
      val = w[k * 128 + j];
    } else {
      if (j < 8) {
        float acc = 0.f;
#pragma unroll
        for (int t = 0; t < 16; ++t) acc += gw[k * 128 + j * 16 + t] * atts[j * 16 + t];
        val = acc;
      } else if (j < 16) {
        int h = j - 8;
        float acc = 0.f;
#pragma unroll
        for (int t = 0; t < 16; ++t) acc += gw[k * 128 + h * 16 + t] * attd[h * 16 + t];
        val = acc;
      } else {
        val = 0.f;
      }
    }
    Wcat_t[i] = f2bf(val);
  } else if (i < 131072) {              // sage_t[128][256]
    int t = i - 98304;
    int j = t >> 8, k = t & 255;
    float v = (k < 128) ? swl[k * 128 + j] : swr[(k - 128) * 128 + j];
    sage_t[t] = f2bf(v);
  } else if (i < 180224) {              // fus_t[128][384]
    int t = i - 131072;
    int j = t / 384, k = t - j * 384;
    fus_t[t] = f2bf(fw[k * 128 + j]);
  } else if (i < 180992) {              // Bcat[768]
    int c = i - 180224;
    int s = c >> 7, j = c & 127;
    Bcat[c] = (s == 1) ? bq[j] : (s == 2) ? bk[j] : (s == 3) ? bv[j] : (s == 4) ? bsk[j] : 0.f;
  }
}

// ---------------- x -> Xb (bf16 GEMM copy) + AG x-slab (fp8) + deg hist
__global__ void conv_hist(const float* __restrict__ x, unsigned short* __restrict__ Xb,
                          unsigned char* __restrict__ AG,
                          const int* __restrict__ ei, int* __restrict__ ideg,
                          int n, int E, int CB) {
  int b = blockIdx.x;
  if (b < CB) {
    int i = b * 256 + threadIdx.x;
    if (i >= n * 32) return;
    int node = i >> 5, c = (i & 31) * 4;
    float4 v = *(const float4*)(x + (size_t)node * 128 + c);
    ushort4 ub = { f2bf(v.x), f2bf(v.y), f2bf(v.z), f2bf(v.w) };
    *(ushort4*)(Xb + (size_t)node * 128 + c) = ub;
    uchar4 u8 = { f_fp8(v.x), f_fp8(v.y), f_fp8(v.z), f_fp8(v.w) };
    *(uchar4*)(AG + (size_t)node * ROWB + 512 + c) = u8;
  } else {
    int t = (b - CB) * 256 + threadIdx.x;
    int stride = (gridDim.x - CB) * 256;
    for (int e = t; e < E; e += stride) atomicAdd(&ideg[ei[E + e]], 1);
  }
}

// ---------------- bf16 MFMA GEMM, tile 128x128, fused epilogues ------
// EPI 0: proj (grid.y: 0=h(fp8), 1=q(bf16), 2=k(bf16), 3=v(fp8), 4=skip(bf16), 5=aS(AG)/aD)
// EPI 1: sage (+bias, L2-normalize row, bf16 -> FUS[:,128:256))
// EPI 2: fusion (+bias, LayerNorm row, f32 out)
template <int EPI>
__global__ __launch_bounds__(256) void gemm128(
    const __hip_bfloat16* __restrict__ A0, int lda0,
    const __hip_bfloat16* __restrict__ A1, int lda1,
    const __hip_bfloat16* __restrict__ Bt, int K,
    const float* __restrict__ bias,
    unsigned char* __restrict__ AGo, unsigned short* __restrict__ Pq,
    unsigned short* __restrict__ Psk, float* __restrict__ aDo,
    unsigned short* __restrict__ FUSo, float* __restrict__ outF,
    const float* __restrict__ lng, const float* __restrict__ lnb,
    int M) {
  __shared__ char Asb[128 * 64];
  __shared__ char Bsb[128 * 64];
  int tid = threadIdx.x;
  int l = tid & 63, w = tid >> 6;
  int row0 = blockIdx.x * 128, col0 = blockIdx.y * 128;
  f32x4 acc[2][8] = {};

  for (int kt = 0; kt < K; kt += 32) {
    const __hip_bfloat16* Ap;
    int lda, kof;
    if (A1 != nullptr && kt >= 128) { Ap = A1; lda = lda1; kof = kt - 128; }
    else { Ap = A0; lda = lda0; kof = kt; }
#pragma unroll
    for (int it = 0; it < 2; ++it) {
      int c = it * 256 + tid;
      int r = c >> 2, cp = c & 3;
      int gp = cp ^ (r & 3);
      int gr = row0 + r; if (gr >= M) gr = M - 1;
      GLD_LDS16((const char*)(Ap + (size_t)gr * lda + kof) + gp * 16, Asb + c * 16);
    }
#pragma unroll
    for (int it = 0; it < 2; ++it) {
      int c = it * 256 + tid;
      int r = c >> 2, cp = c & 3;
      int gp = cp ^ (r & 3);
      GLD_LDS16((const char*)(Bt + (size_t)(col0 + r) * K + kt) + gp * 16, Bsb + c * 16);
    }
    __syncthreads();
    int g = l >> 4, ri = l & 15;
    short8 af[2], bfr[8];
#pragma unroll
    for (int m = 0; m < 2; ++m) {
      int r = w * 32 + m * 16 + ri;
      af[m] = *(const short8*)(Asb + r * 64 + ((g ^ (r & 3)) * 16));
    }
#pragma unroll
    for (int c4 = 0; c4 < 8; ++c4) {
      int r = c4 * 16 + ri;
      bfr[c4] = *(const short8*)(Bsb + r * 64 + ((g ^ (r & 3)) * 16));
    }
#pragma unroll
    for (int m = 0; m < 2; ++m)
#pragma unroll
      for (int c4 = 0; c4 < 8; ++c4)
        acc[m][c4] = __builtin_amdgcn_mfma_f32_16x16x32_bf16(af[m], bfr[c4], acc[m][c4], 0, 0, 0);
    __syncthreads();
  }

  int g = l >> 4, ri = l & 15;
  float bias_r[8];
#pragma unroll
  for (int c4 = 0; c4 < 8; ++c4) bias_r[c4] = bias[col0 + c4 * 16 + ri];

  if (EPI == 0) {
    int y = col0 >> 7;  // 0..5
    if (y == 5) {
#pragma unroll
      for (int m = 0; m < 2; ++m) {
#pragma unroll
        for (int j = 0; j < 4; ++j) {
          int row = row0 + w * 32 + m * 16 + g * 4 + j;
          if (row >= M) continue;
          float v = acc[m][0][j];
          if (ri < 8) *(float*)(AGo + (size_t)row * ROWB + 640 + ri * 4) = v;
          else        aDo[row * HEADS + (ri - 8)] = v;
        }
      }
    } else {
#pragma unroll
      for (int m = 0; m < 2; ++m) {
#pragma unroll
        for (int j = 0; j < 4; ++j) {
          int row = row0 + w * 32 + m * 16 + g * 4 + j;
          if (row >= M) continue;
#pragma unroll
          for (int c4 = 0; c4 < 8; ++c4) {
            int c = c4 * 16 + ri;
            float v = acc[m][c4][j] + bias_r[c4];
            if (y == 0)      AGo[(size_t)row * ROWB + 256 + c] = f_fp8(v);
            else if (y == 1) Pq[(size_t)row * 128 + c] = f2bf(v);
            else if (y == 2) *(unsigned short*)(AGo + (size_t)row * ROWB + c * 2) = f2bf(v);
            else if (y == 3) AGo[(size_t)row * ROWB + 384 + c] = f_fp8(v);
            else             Psk[(size_t)row * 128 + c] = f2bf(v);
          }
        }
      }
    }
  } else {
#pragma unroll
    for (int m = 0; m < 2; ++m) {
#pragma unroll
      for (int j = 0; j < 4; ++j) {
        int row = row0 + w * 32 + m * 16 + g * 4 + j;
        bool ok = (row < M);
        float v[8];
        float s = 0.f;
#pragma unroll
        for (int c4 = 0; c4 < 8; ++c4) {
          v[c4] = acc[m][c4][j] + bias_r[c4];
          if (EPI == 1) s += v[c4] * v[c4];
          else          s += v[c4];
        }
        s += __shfl_xor(s, 1); s += __shfl_xor(s, 2);
        s += __shfl_xor(s, 4); s += __shfl_xor(s, 8);
        if (EPI == 1) {
          float inv = 1.f / fmaxf(sqrtf(s), 1e-12f);
          if (ok) {
#pragma unroll
            for (int c4 = 0; c4 < 8; ++c4)
              FUSo[(size_t)row * 384 + 128 + c4 * 16 + ri] = f2bf(v[c4] * inv);
          }
        } else {
          float mu = s * (1.f / 128.f);
          float ss = 0.f;
#pragma unroll
          for (int c4 = 0; c4 < 8; ++c4) { float d = v[c4] - mu; ss += d * d; }
          ss += __shfl_xor(ss, 1); ss += __shfl_xor(ss, 2);
          ss += __shfl_xor(ss, 4); ss += __shfl_xor(ss, 8);
          float rstd = 1.f / sqrtf(ss * (1.f / 128.f) + 1e-5f);
          if (ok) {
#pragma unroll
            for (int c4 = 0; c4 < 8; ++c4) {
              int c = c4 * 16 + ri;
              outF[(size_t)row * 128 + c] = (v[c4] - mu) * rstd * lng[c] + lnb[c];
            }
          }
        }
      }
    }
  }
}

// ---------------- CSR build (hierarchical scan) ---------------------
__global__ void bsum_k(const int* __restrict__ deg, int* __restrict__ bsum, int n) {
  int blk = blockIdx.x, t = threadIdx.x;
  int base = blk * 1024 + t * 4;
  int s = 0;
  if (base + 3 < n) {
    int4 d = *(const int4*)(deg + base);
    s = d.x + d.y + d.z + d.w;
  } else {
#pragma unroll
    for (int j = 0; j < 4; ++j) { int i = base + j; if (i < n) s += deg[i]; }
  }
  int lane = t & 63, wid = t >> 6;
  int x = s;
#pragma unroll
  for (int d = 1; d < 64; d <<= 1) { int y = __shfl_up(x, d); if (lane >= d) x += y; }
  __shared__ int wsum[4];
  if (lane == 63) wsum[wid] = x;
  __syncthreads();
  if (t == 0) bsum[blk] = wsum[0] + wsum[1] + wsum[2] + wsum[3];
}

__global__ void bscan_k(const int* __restrict__ bsum, int* __restrict__ bpref,
                        int* __restrict__ total_out, int nb) {
  int lane = threadIdx.x;
  int carry = 0;
  for (int base = 0; base < nb; base += 64) {
    int i = base + lane;
    int v = (i < nb) ? bsum[i] : 0;
    int x = v;
#pragma unroll
    for (int d = 1; d < 64; d <<= 1) { int y = __shfl_up(x, d); if (lane >= d) x += y; }
    if (i < nb) bpref[i] = carry + x - v;
    carry += __shfl(x, 63);
  }
  if (lane == 0) total_out[0] = carry;
}

__global__ void offs_k(const int* __restrict__ deg, const int* __restrict__ bpref,
                       int* __restrict__ offs, int* __restrict__ cursor, int n) {
  int blk = blockIdx.x, t = threadIdx.x;
  int base = blk * 1024 + t * 4;
  int d0 = 0, d1 = 0, d2 = 0, d3 = 0;
  if (base + 3 < n) {
    int4 d = *(const int4*)(deg + base);
    d0 = d.x; d1 = d.y; d2 = d.z; d3 = d.w;
  } else {
    if (base + 0 < n) d0 = deg[base + 0];
    if (base + 1 < n) d1 = deg[base + 1];
    if (base + 2 < n) d2 = deg[base + 2];
    if (base + 3 < n) d3 = deg[base + 3];
  }
  int s = d0 + d1 + d2 + d3;
  int lane = t & 63, wid = t >> 6;
  int x = s;
#pragma unroll
  for (int d = 1; d < 64; d <<= 1) { int y = __shfl_up(x, d); if (lane >= d) x += y; }
  __shared__ int wsum[4];
  if (lane == 63) wsum[wid] = x;
  __syncthreads();
  int woff = 0;
  for (int ww = 0; ww < wid; ++ww) woff += wsum[ww];
  int excl = bpref[blk] + woff + x - s;
  int p0 = excl, p1 = excl + d0, p2 = p1 + d1, p3 = p2 + d2;
  if (base + 0 < n) { offs[base + 0] = p0; cursor[base + 0] = p0; }
  if (base + 1 < n) { offs[base + 1] = p1; cursor[base + 1] = p1; }
  if (base + 2 < n) { offs[base + 2] = p2; cursor[base + 2] = p2; }
  if (base + 3 < n) { offs[base + 3] = p3; cursor[base + 3] = p3; }
}

__global__ void scatter_k(const int* __restrict__ ei, int* __restrict__ cursor,
                          int* __restrict__ csrc, int E) {
  int e = blockIdx.x * 256 + threadIdx.x;
  if (e >= E) return;
  int src = ei[e], dst = ei[E + e];
  int pos = atomicAdd(&cursor[dst], 1);
  csrc[pos] = src;
}

// ---------------- per-node aggregation ------------------------------
// unnormalized softmax; 8-edge batching; 6-line (768B) aligned row gathers
__global__ __launch_bounds__(256) void aggregate(
    const unsigned char* __restrict__ AG, const unsigned short* __restrict__ Pq,
    const unsigned short* __restrict__ Psk, const float* __restrict__ aD,
    const int* __restrict__ offs, const int* __restrict__ csrc,
    const float* __restrict__ gat_b,
    unsigned short* __restrict__ FUS, unsigned short* __restrict__ nbrb, int n) {
  int node = blockIdx.x * 4 + (threadIdx.x >> 6);
  if (node >= n) return;
  int lane = threadIdx.x & 63;
  int head = lane >> 3;
  unsigned int qu = *(const unsigned int*)(Pq + (size_t)node * 128 + 2 * lane);
  float2 qv = { u_lo(qu), u_hi(qu) };
  float adst = aD[node * HEADS + head];

  const unsigned char* An = AG + (size_t)node * ROWB;
  float lg0 = *(const float*)(An + 640 + head * 4) + adst;
  lg0 = fmaxf(lg0, 0.2f * lg0);
  float w0 = __expf(lg0);
  unsigned short h0raw = *(const unsigned short*)(An + 256 + lane * 2);
  float2 acc_g = { w0 * fp8_f((unsigned char)(h0raw & 0xff)),
                   w0 * fp8_f((unsigned char)(h0raw >> 8)) };
  float l_g = w0;

  float l_t = 0.f;
  float2 acc_t = {0.f, 0.f};
  float2 acc_s = {0.f, 0.f};

  int e0 = offs[node], e1 = offs[node + 1];

#define EDGE_UPDATE(KU, HR, VR, XR, AV)                                  \
  {                                                                      \
    float lg = (AV) + adst;                                              \
    lg = fmaxf(lg, 0.2f * lg);                                           \
    float wg = __expf(lg);                                               \
    acc_g.x += wg * fp8_f((unsigned char)((HR) & 0xff));                 \
    acc_g.y += wg * fp8_f((unsigned char)((HR) >> 8));                   \
    l_g += wg;                                                           \
    float part = qv.x * u_lo(KU) + qv.y * u_hi(KU);                      \
    part += __shfl_xor(part, 1);                                         \
    part += __shfl_xor(part, 2);                                         \
    part += __shfl_xor(part, 4);                                         \
    float wt = __expf(part * 0.25f);                                     \
    acc_t.x += wt * fp8_f((unsigned char)((VR) & 0xff));                 \
    acc_t.y += wt * fp8_f((unsigned char)((VR) >> 8));                   \
    l_t += wt;                                                           \
    acc_s.x += fp8_f((unsigned char)((XR) & 0xff));                      \
    acc_s.y += fp8_f((unsigned char)((XR) >> 8));                        \
  }

#define LOAD_EDGE(u, si_a, ku_a, hr_a, vr_a, xr_a, av_a)                 \
  {                                                                      \
    const unsigned char* As = AG + (size_t)si_a[u] * ROWB;               \
    ku_a[u] = *(const unsigned int*)(As + lane * 4);                     \
    hr_a[u] = *(const unsigned short*)(As + 256 + lane * 2);             \
    vr_a[u] = *(const unsigned short*)(As + 384 + lane * 2);             \
    xr_a[u] = *(const unsigned short*)(As + 512 + lane * 2);             \
    av_a[u] = *(const float*)(As + 640 + head * 4);                      \
  }

  int e = e0;
  for (; e + 8 <= e1; e += 8) {
    int si[8];
#pragma unroll
    for (int u = 0; u < 8; ++u) si[u] = csrc[e + u];
    unsigned int ku[8];
    unsigned short hr[8], vr[8], xr[8];
    float av[8];
#pragma unroll
    for (int u = 0; u < 8; ++u) LOAD_EDGE(u, si, ku, hr, vr, xr, av);
#pragma unroll
    for (int u = 0; u < 8; ++u) EDGE_UPDATE(ku[u], hr[u], vr[u], xr[u], av[u]);
  }
  if (e + 4 <= e1) {
    int si[4];
#pragma unroll
    for (int u = 0; u < 4; ++u) si[u] = csrc[e + u];
    unsigned int ku[4];
    unsigned short hr[4], vr[4], xr[4];
    float av[4];
#pragma unroll
    for (int u = 0; u < 4; ++u) LOAD_EDGE(u, si, ku, hr, vr, xr, av);
#pragma unroll
    for (int u = 0; u < 4; ++u) EDGE_UPDATE(ku[u], hr[u], vr[u], xr[u], av[u]);
    e += 4;
  }
  for (; e < e1; ++e) {
    int s = csrc[e];
    const unsigned char* As = AG + (size_t)s * ROWB;
    unsigned int ku = *(const unsigned int*)(As + lane * 4);
    unsigned short hr = *(const unsigned short*)(As + 256 + lane * 2);
    unsigned short vr = *(const unsigned short*)(As + 384 + lane * 2);
    unsigned short xr = *(const unsigned short*)(As + 512 + lane * 2);
    float av = *(const float*)(As + 640 + head * 4);
    EDGE_UPDATE(ku, hr, vr, xr, av);
  }
#undef EDGE_UPDATE
#undef LOAD_EDGE

  float gx = acc_g.x / l_g + gat_b[2 * lane];
  float gy = acc_g.y / l_g + gat_b[2 * lane + 1];
  ushort2 go = { f2bf(gx), f2bf(gy) };
  *(ushort2*)(FUS + (size_t)node * 384 + 2 * lane) = go;

  unsigned int sku = *(const unsigned int*)(Psk + (size_t)node * 128 + 2 * lane);
  float skx = u_lo(sku), sky = u_hi(sku);
  float tx, ty;
  if (l_t > 0.f) {
    tx = acc_t.x / l_t + skx;
    ty = acc_t.y / l_t + sky;
  } else { tx = skx; ty = sky; }
  ushort2 to = { f2bf(tx), f2bf(ty) };
  *(ushort2*)(FUS + (size_t)node * 384 + 256 + 2 * lane) = to;

  float dg = fmaxf((float)(e1 - e0), 1.f);
  float inv = 1.f / dg;
  ushort2 nb = { f2bf(acc_s.x * inv), f2bf(acc_s.y * inv) };
  *(ushort2*)(nbrb + (size_t)node * 128 + 2 * lane) = nb;
}

extern "C" void kernel_launch(void* const* d_in, const int* in_sizes, int n_in,
                              void* d_out, int out_size, void* d_ws, size_t ws_size,
                              hipStream_t stream) {
  const float* x      = (const float*)d_in[0];
  const int*   ei     = (const int*)d_in[1];
  const float* gat_w  = (const float*)d_in[2];
  const float* att_s  = (const float*)d_in[3];
  const float* att_d  = (const float*)d_in[4];
  const float* gat_b  = (const float*)d_in[5];
  const float* swl    = (const float*)d_in[6];
  const float* sbl    = (const float*)d_in[7];
  const float* swr    = (const float*)d_in[8];
  const float* wq     = (const float*)d_in[9];
  const float* bq     = (const float*)d_in[10];
  const float* wk     = (const float*)d_in[11];
  const float* bk     = (const float*)d_in[12];
  const float* wv     = (const float*)d_in[13];
  const float* bv     = (const float*)d_in[14];
  const float* wsk    = (const float*)d_in[15];
  const float* bsk    = (const float*)d_in[16];
  const float* fus_w  = (const float*)d_in[17];
  const float* fus_b  = (const float*)d_in[18];
  const float* ln_g   = (const float*)d_in[19];
  const float* ln_b   = (const float*)d_in[20];
  float* out = (float*)d_out;

  const int n = in_sizes[0] / DIM;  // 50000
  const int E = in_sizes[1] / 2;    // 800000

  char* wsb = (char*)d_ws;
  size_t o = 0;
  auto carve = [&](size_t bytes) { char* p = wsb + o; o += (bytes + 255) & ~(size_t)255; return p; };
  unsigned short* Wcat_t = (unsigned short*)carve(768 * 128 * 2);
  float*          Bcat   = (float*)carve(768 * 4);
  unsigned short* sage_t = (unsigned short*)carve(128 * 256 * 2);
  unsigned short* fus_t  = (unsigned short*)carve(128 * 384 * 2);
  unsigned char*  AG     = (unsigned char*)carve((size_t)n * ROWB);
  unsigned short* Xb     = (unsigned short*)carve((size_t)n * 128 * 2);
  unsigned short* Pqs    = (unsigned short*)carve((size_t)n * 128 * 2);
  unsigned short* Psk    = (unsigned short*)carve((size_t)n * 128 * 2);
  float*          aDa    = (float*)carve((size_t)n * HEADS * 4);
  unsigned short* FUS    = (unsigned short*)carve((size_t)n * 384 * 2);
  unsigned short* nbrb   = (unsigned short*)carve((size_t)n * 128 * 2);
  int* ideg   = (int*)carve((size_t)n * 4);
  int* offs   = (int*)carve(((size_t)n + 1) * 4);
  int* cursor = (int*)carve((size_t)n * 4);
  int* csrc   = (int*)carve((size_t)E * 4);
  const int NB = (n + 1023) / 1024;
  int* bsum   = (int*)carve((size_t)NB * 4);
  int* bpref  = (int*)carve((size_t)NB * 4);

  hipMemsetAsync(ideg, 0, n * sizeof(int), stream);

  prep_w<<<(180992 + 255) / 256, 256, 0, stream>>>(
      gat_w, wq, wk, wv, wsk, bq, bk, bv, bsk, att_s, att_d, swl, swr, fus_w,
      Wcat_t, Bcat, sage_t, fus_t);

  const int CB = (n * 32 + 255) / 256;           // convert blocks
  const int HB = (E + 255) / 256 / 2;            // hist blocks (grid-stride x2)
  conv_hist<<<CB + HB, 256, 0, stream>>>(x, Xb, AG, ei, ideg, n, E, CB);

  const int RB = (n + 127) / 128;  // 391

  // proj: [h q k v skip aS aD] = x @ Wcat + Bcat; y tile routes
  gemm128<0><<<dim3(RB, 6), 256, 0, stream>>>(
      (const __hip_bfloat16*)Xb, 128, nullptr, 0,
      (const __hip_bfloat16*)Wcat_t, 128, Bcat,
      AG, Pqs, Psk, aDa, nullptr, nullptr, nullptr, nullptr, n);

  bsum_k<<<NB, 256, 0, stream>>>(ideg, bsum, n);
  bscan_k<<<1, 64, 0, stream>>>(bsum, bpref, offs + n, NB);
  offs_k<<<NB, 256, 0, stream>>>(ideg, bpref, offs, cursor, n);
  scatter_k<<<(E + 255) / 256, 256, 0, stream>>>(ei, cursor, csrc, E);

  aggregate<<<(n + 3) / 4, 256, 0, stream>>>(AG, Pqs, Psk, aDa, offs, csrc,
                                             gat_b, FUS, nbrb, n);

  // sage: [nbr | x] @ [swl; swr] + sbl, L2-normalized -> FUS[:,128:256)
  gemm128<1><<<dim3(RB, 1), 256, 0, stream>>>(
      (const __hip_bfloat16*)nbrb, 128, (const __hip_bfloat16*)Xb, 128,
      (const __hip_bfloat16*)sage_t, 256, sbl,
      nullptr, nullptr, nullptr, nullptr,
      FUS, nullptr, nullptr, nullptr, n);

  // out = FUS @ fus_w + fus_b, LayerNorm fused
  gemm128<2><<<dim3(RB, 1), 256, 0, stream>>>(
      (const __hip_bfloat16*)FUS, 384, nullptr, 0,
      (const __hip_bfloat16*)fus_t, 384, fus_b,
      nullptr, nullptr, nullptr, nullptr,
      nullptr, out, ln_g, ln_b, n);
}